// Round 12
// baseline (3409.399 us; speedup 1.0000x reference)
//
#include <hip/hip_runtime.h>
#include <hip/hip_bf16.h>
#include <math.h>

// ============================================================================
// BEiT ViT-B/16 forward — round 12: r9 champion base with ONE change:
// exact counted vmcnt in both GEMM loops (mm256 vmcnt(2)->(3), mm128
// vmcnt(3)->(4)) — removes the over-drain-by-1 fresh-load stall per K-tile.
// Everything else identical to r9 (best measured, 3296 us).
// ============================================================================

typedef __hip_bfloat16 bf16;
using short8 = __attribute__((ext_vector_type(8))) short;
using f32x4  = __attribute__((ext_vector_type(4))) float;

#define NTOK 197
#define NHEAD 12
#define NPAD 224

#define S_QKV  1769472
#define S_PROJ 589824
#define S_FC   2359296
#define O_PROJ 1769472
#define O_FC1  2359296
#define O_FC2  4718592
#define W_TOT  7077888

#define GLD(gp, lp) __builtin_amdgcn_global_load_lds( \
    (const unsigned int __attribute__((address_space(1)))*)(gp), \
    (unsigned int __attribute__((address_space(3)))*)(lp), 16, 0, 0)

// ---------------- fp32 -> bf16 convert (patch_w) -----------------------------
__global__ __launch_bounds__(256) void cvt_k(const float* __restrict__ src,
                                             bf16* __restrict__ dst, int n8) {
  int t = blockIdx.x * 256 + threadIdx.x;
  if (t >= n8) return;
  size_t i = (size_t)t * 8;
  float4 a = *(const float4*)(src + i);
  float4 b = *(const float4*)(src + i + 4);
  union { short8 v; bf16 e[8]; } u;
  u.e[0] = __float2bfloat16(a.x); u.e[1] = __float2bfloat16(a.y);
  u.e[2] = __float2bfloat16(a.z); u.e[3] = __float2bfloat16(a.w);
  u.e[4] = __float2bfloat16(b.x); u.e[5] = __float2bfloat16(b.y);
  u.e[6] = __float2bfloat16(b.z); u.e[7] = __float2bfloat16(b.w);
  *(short8*)(dst + i) = u.v;
}

// ---------------- BEiT relative-position index -------------------------------
__device__ __forceinline__ int ridx(int n, int m) {
  if (n == 0) return (m == 0) ? 731 : 729;
  if (m == 0) return 730;
  int nh = (n - 1) / 14, nw = (n - 1) % 14;
  int mh = (m - 1) / 14, mw = (m - 1) % 14;
  return (nh - mh + 13) * 27 + (nw - mw + 13);
}

// ---------------- fused per-layer prep: weight cvt + bias table --------------
__global__ __launch_bounds__(256) void prep_k(
    const float* __restrict__ qkvw, const float* __restrict__ projw,
    const float* __restrict__ fc1w, const float* __restrict__ fc2w,
    const float* __restrict__ rel, bf16* __restrict__ wl,
    float* __restrict__ biasT, int d) {
  int blk = blockIdx.x;
  if (blk < 3456) {
    size_t i = ((size_t)blk * 256 + threadIdx.x) * 8;
    const float* src;
    if (i < O_PROJ)      src = qkvw + (size_t)d * S_QKV + i;
    else if (i < O_FC1)  src = projw + (size_t)d * S_PROJ + (i - O_PROJ);
    else if (i < O_FC2)  src = fc1w + (size_t)d * S_FC + (i - O_FC1);
    else                 src = fc2w + (size_t)d * S_FC + (i - O_FC2);
    float4 a = *(const float4*)src;
    float4 b = *(const float4*)(src + 4);
    union { short8 v; bf16 e[8]; } u;
    u.e[0] = __float2bfloat16(a.x); u.e[1] = __float2bfloat16(a.y);
    u.e[2] = __float2bfloat16(a.z); u.e[3] = __float2bfloat16(a.w);
    u.e[4] = __float2bfloat16(b.x); u.e[5] = __float2bfloat16(b.y);
    u.e[6] = __float2bfloat16(b.z); u.e[7] = __float2bfloat16(b.w);
    *(short8*)(wl + i) = u.v;
  } else {
    int idx = (blk - 3456) * 256 + threadIdx.x;
    int h = idx / (NPAD * 256);
    int rem = idx % (NPAD * 256);
    int m = rem / 256, n = rem % 256;
    float v;
    if (m >= NTOK) {
      v = -1e30f;
    } else {
      int nn = min(n, NTOK - 1);
      v = rel[((size_t)d * 732 + ridx(nn, m)) * 12 + h];
    }
    biasT[idx] = v;
  }
}

// ---------------- patchify ---------------------------------------------------
__global__ __launch_bounds__(256) void patchify_k(const float* __restrict__ x,
                                                  bf16* __restrict__ patches) {
  int o = blockIdx.x * 256 + threadIdx.x;
  if (o >= 6272 * 768) return;
  int row = o / 768, col = o % 768;
  int b = row / 196, g = row % 196;
  int gh = g / 14, gw = g % 14;
  int c = col / 256, r = col % 256;
  int ph = r / 16, pw = r % 16;
  patches[o] = __float2bfloat16(
      x[(((size_t)b * 3 + c) * 224 + gh * 16 + ph) * 224 + gw * 16 + pw]);
}

// ---------------- cls token fill ---------------------------------------------
__global__ __launch_bounds__(256) void clsfill_k(const float* __restrict__ cls,
                                                 float* __restrict__ h) {
  int i = blockIdx.x * 256 + threadIdx.x;
  if (i >= 32 * 768) return;
  int b = i / 768, e = i % 768;
  h[((size_t)b * 197) * 768 + e] = cls[e];
}

// ---------------- zero vt ----------------------------------------------------
__global__ __launch_bounds__(256) void vtz_k(bf16* __restrict__ vt) {
  int i = blockIdx.x * 256 + threadIdx.x;
  if (i >= 32 * 12 * 64 * NPAD / 8) return;
  *(short8*)(vt + (size_t)i * 8) = (short8){0,0,0,0,0,0,0,0};
}

// ============================================================================
// mm256: 3-ring counted-vmcnt MFMA GEMM, BM=256 x BN=128, BK=32, 512 thr /
// 8 waves (4m x 2n), per-wave 64x64. LDS = 3 x 24KB = 72KB.
// Prologue vmcnt(3); loop vmcnt(3) (EXACT: drains t+1's 3, keeps t+2's 3).
// EPI: 1=qkv (split bias, Q/K->bf16, V->vt), 3=fc1 (bias+gelu->bf16).
// ============================================================================
template <int EPI>
__global__ __launch_bounds__(512, 4) void mm256_k(
    const bf16* __restrict__ A, const bf16* __restrict__ W,
    const float* __restrict__ bias, const float* __restrict__ bias2,
    void* __restrict__ Cout, bf16* __restrict__ vtg,
    int M, int Nn, int K) {
  constexpr int BUFSZ = 24576;
  __shared__ __attribute__((aligned(16))) char lds[3 * BUFSZ];
  const int tid = threadIdx.x;
  const int lane = tid & 63, wave = tid >> 6;
  const int wr = wave >> 1, wc = wave & 1;
  const int l15 = lane & 15, lg = lane >> 4;
  const int row0 = blockIdx.x * 256, n0 = blockIdx.y * 128;
  const int nt = K >> 5, ntm1 = nt - 1;

  const bf16 *gA0, *gA1, *gB0;
  int dA0, dA1, dB0;
  {
    int s = tid * 16;
    int r = s >> 6, cl = ((s >> 4) & 3) ^ ((r >> 1) & 3);
    gA0 = A + (size_t)(row0 + r) * K + cl * 8;  dA0 = s;
    s = 8192 + tid * 16;
    r = s >> 6; cl = ((s >> 4) & 3) ^ ((r >> 1) & 3);
    gA1 = A + (size_t)(row0 + r) * K + cl * 8;  dA1 = s;
    s = tid * 16;
    r = s >> 6; cl = ((s >> 4) & 3) ^ ((r >> 1) & 3);
    gB0 = W + (size_t)(n0 + r) * K + cl * 8;    dB0 = 16384 + s;
  }
  int oA[4], oB[4];
#pragma unroll
  for (int m = 0; m < 4; m++) {
    int r = wr * 64 + m * 16 + l15;
    oA[m] = (r << 6) | ((lg ^ ((r >> 1) & 3)) << 4);
  }
#pragma unroll
  for (int n = 0; n < 4; n++) {
    int r = wc * 64 + n * 16 + l15;
    oB[n] = 16384 + ((r << 6) | ((lg ^ ((r >> 1) & 3)) << 4));
  }

  f32x4 acc[4][4];
#pragma unroll
  for (int m = 0; m < 4; m++)
#pragma unroll
    for (int n = 0; n < 4; n++) acc[m][n] = (f32x4){0.f, 0.f, 0.f, 0.f};

  GLD(gA0, lds + dA0); GLD(gA1, lds + dA1); GLD(gB0, lds + dB0);
  GLD(gA0 + 32, lds + BUFSZ + dA0); GLD(gA1 + 32, lds + BUFSZ + dA1);
  GLD(gB0 + 32, lds + BUFSZ + dB0);
  asm volatile("s_waitcnt vmcnt(3)" ::: "memory");
  __builtin_amdgcn_s_barrier();
  __builtin_amdgcn_sched_barrier(0);

#define MB(RB, WB, tt)                                                        \
  {                                                                           \
    int ks = (tt) + 2; if (ks > ntm1) ks = ntm1; ks <<= 5;                    \
    char* wb = lds + (WB) * BUFSZ;                                            \
    GLD(gA0 + ks, wb + dA0); GLD(gA1 + ks, wb + dA1);                         \
    GLD(gB0 + ks, wb + dB0);                                                  \
    const char* rb = lds + (RB) * BUFSZ;                                      \
    short8 a[4], b[4];                                                        \
    _Pragma("unroll") for (int m = 0; m < 4; m++)                             \
      a[m] = *(const short8*)(rb + oA[m]);                                    \
    _Pragma("unroll") for (int n = 0; n < 4; n++)                             \
      b[n] = *(const short8*)(rb + oB[n]);                                    \
    __builtin_amdgcn_s_setprio(1);                                            \
    _Pragma("unroll") for (int m = 0; m < 4; m++)                             \
      _Pragma("unroll") for (int n = 0; n < 4; n++)                           \
        acc[m][n] = __builtin_amdgcn_mfma_f32_16x16x32_bf16(a[m], b[n], acc[m][n], 0, 0, 0); \
    __builtin_amdgcn_s_setprio(0);                                            \
    __builtin_amdgcn_sched_barrier(0);                                        \
    asm volatile("s_waitcnt vmcnt(3)" ::: "memory");                          \
    __builtin_amdgcn_s_barrier();                                             \
    __builtin_amdgcn_sched_barrier(0);                                        \
  }

  for (int t = 0; t < nt; t += 3) {  // nt % 3 == 0
    MB(0, 2, t); MB(1, 0, t + 1); MB(2, 1, t + 2);
  }
#undef MB
  asm volatile("s_waitcnt vmcnt(0)" ::: "memory");

#pragma unroll
  for (int m = 0; m < 4; m++) {
    const int rbase = row0 + wr * 64 + m * 16 + lg * 4;
#pragma unroll
    for (int n = 0; n < 4; n++) {
      const int gc = n0 + wc * 64 + n * 16 + l15;
      f32x4 v = acc[m][n];
#pragma unroll
      for (int j = 0; j < 4; j++) {
        int gr = rbase + j;
        if (gr >= M) continue;
        float val = v[j];
        if (EPI == 1) {
          if (gc < 768) val += bias[gc];
          else if (gc >= 1536) val += bias2[gc - 1536];
          if (gc >= 1536) {
            int ob = gr / 197, nn = gr - ob * 197, hd = gc - 1536;
            vtg[(((size_t)ob * 12 + (hd >> 6)) * 64 + (hd & 63)) * NPAD + nn] =
                __float2bfloat16(val);
          } else {
            ((bf16*)Cout)[(size_t)gr * Nn + gc] = __float2bfloat16(val);
          }
        } else {  // EPI == 3
          val += bias[gc];
          val = 0.5f * val * (1.f + erff(val * 0.70710678118654752f));
          ((bf16*)Cout)[(size_t)gr * Nn + gc] = __float2bfloat16(val);
        }
      }
    }
  }
}

// ============================================================================
// mm128: 3-ring counted-vmcnt, BM=BN=128, BK=32, 256 thr / 4 waves (2x2),
// per-wave 64x64. LDS = 48KB -> 3 blocks/CU.
// Prologue vmcnt(4); loop vmcnt(4) (EXACT: drains t+1's 4, keeps t+2's 4).
// EPI: 0=patch (bias, f32, remap), 2=bias+residual (f32) [proj, fc2].
// ============================================================================
template <int EPI>
__global__ __launch_bounds__(256, 3) void mm128_k(
    const bf16* __restrict__ A, const bf16* __restrict__ W,
    const float* __restrict__ bias, const float* __restrict__ Res,
    void* __restrict__ Cout, int M, int Nn, int K) {
  constexpr int BUFSZ = 16384;
  __shared__ __attribute__((aligned(16))) char lds[3 * BUFSZ];
  const int tid = threadIdx.x;
  const int lane = tid & 63, wave = tid >> 6;
  const int wr = wave >> 1, wc = wave & 1;
  const int l15 = lane & 15, lg = lane >> 4;
  const int row0 = blockIdx.x * 128, n0 = blockIdx.y * 128;
  const int nt = K >> 5, ntm1 = nt - 1;

  const bf16 *gA0, *gA1, *gB0, *gB1;
  int dA0, dA1, dB0, dB1;
  {
    int s = tid * 16;
    int r = s >> 6, cl = ((s >> 4) & 3) ^ ((r >> 1) & 3);
    gA0 = A + (size_t)(row0 + r) * K + cl * 8;  dA0 = s;
    s = 4096 + tid * 16;
    r = s >> 6; cl = ((s >> 4) & 3) ^ ((r >> 1) & 3);
    gA1 = A + (size_t)(row0 + r) * K + cl * 8;  dA1 = s;
    s = tid * 16;
    r = s >> 6; cl = ((s >> 4) & 3) ^ ((r >> 1) & 3);
    gB0 = W + (size_t)(n0 + r) * K + cl * 8;    dB0 = 8192 + s;
    s = 4096 + tid * 16;
    r = s >> 6; cl = ((s >> 4) & 3) ^ ((r >> 1) & 3);
    gB1 = W + (size_t)(n0 + r) * K + cl * 8;    dB1 = 8192 + s;
  }
  int oA[4], oB[4];
#pragma unroll
  for (int m = 0; m < 4; m++) {
    int r = wr * 64 + m * 16 + l15;
    oA[m] = (r << 6) | ((lg ^ ((r >> 1) & 3)) << 4);
  }
#pragma unroll
  for (int n = 0; n < 4; n++) {
    int r = wc * 64 + n * 16 + l15;
    oB[n] = 8192 + ((r << 6) | ((lg ^ ((r >> 1) & 3)) << 4));
  }

  f32x4 acc[4][4];
#pragma unroll
  for (int m = 0; m < 4; m++)
#pragma unroll
    for (int n = 0; n < 4; n++) acc[m][n] = (f32x4){0.f, 0.f, 0.f, 0.f};

  GLD(gA0, lds + dA0); GLD(gA1, lds + dA1);
  GLD(gB0, lds + dB0); GLD(gB1, lds + dB1);
  GLD(gA0 + 32, lds + BUFSZ + dA0); GLD(gA1 + 32, lds + BUFSZ + dA1);
  GLD(gB0 + 32, lds + BUFSZ + dB0); GLD(gB1 + 32, lds + BUFSZ + dB1);
  asm volatile("s_waitcnt vmcnt(4)" ::: "memory");
  __builtin_amdgcn_s_barrier();
  __builtin_amdgcn_sched_barrier(0);

#define MB(RB, WB, tt)                                                        \
  {                                                                           \
    int ks = (tt) + 2; if (ks > ntm1) ks = ntm1; ks <<= 5;                    \
    char* wb = lds + (WB) * BUFSZ;                                            \
    GLD(gA0 + ks, wb + dA0); GLD(gA1 + ks, wb + dA1);                         \
    GLD(gB0 + ks, wb + dB0); GLD(gB1 + ks, wb + dB1);                         \
    const char* rb = lds + (RB) * BUFSZ;                                      \
    short8 a[4], b[4];                                                        \
    _Pragma("unroll") for (int m = 0; m < 4; m++)                             \
      a[m] = *(const short8*)(rb + oA[m]);                                    \
    _Pragma("unroll") for (int n = 0; n < 4; n++)                             \
      b[n] = *(const short8*)(rb + oB[n]);                                    \
    __builtin_amdgcn_s_setprio(1);                                            \
    _Pragma("unroll") for (int m = 0; m < 4; m++)                             \
      _Pragma("unroll") for (int n = 0; n < 4; n++)                           \
        acc[m][n] = __builtin_amdgcn_mfma_f32_16x16x32_bf16(a[m], b[n], acc[m][n], 0, 0, 0); \
    __builtin_amdgcn_s_setprio(0);                                            \
    __builtin_amdgcn_sched_barrier(0);                                        \
    asm volatile("s_waitcnt vmcnt(4)" ::: "memory");                          \
    __builtin_amdgcn_s_barrier();                                             \
    __builtin_amdgcn_sched_barrier(0);                                        \
  }

  for (int t = 0; t < nt; t += 3) {  // nt % 3 == 0
    MB(0, 2, t); MB(1, 0, t + 1); MB(2, 1, t + 2);
  }
#undef MB
  asm volatile("s_waitcnt vmcnt(0)" ::: "memory");

#pragma unroll
  for (int m = 0; m < 4; m++) {
    const int rbase = row0 + wr * 64 + m * 16 + lg * 4;
#pragma unroll
    for (int n = 0; n < 4; n++) {
      const int gc = n0 + wc * 64 + n * 16 + l15;
      f32x4 v = acc[m][n];
#pragma unroll
      for (int j = 0; j < 4; j++) {
        int gr = rbase + j;
        if (gr >= M) continue;
        float val = v[j] + bias[gc];
        if (EPI == 2) val += Res[(size_t)gr * Nn + gc];
        int orow = (EPI == 0) ? (gr + gr / 196 + 1) : gr;
        ((float*)Cout)[(size_t)orow * Nn + gc] = val;
      }
    }
  }
}

// ---------------- LayerNorm (768), fp32 in -> bf16 out, vectorized ----------
__global__ __launch_bounds__(256) void ln_k(const float* __restrict__ in,
                                            bf16* __restrict__ outp,
                                            const float* __restrict__ w,
                                            const float* __restrict__ b,
                                            int rows) {
  int row = blockIdx.x * 4 + threadIdx.y;
  if (row >= rows) return;
  int lane = threadIdx.x;
  const float4* xr = (const float4*)(in + (size_t)row * 768);
  float4 v[3];
  float s = 0.f;
#pragma unroll
  for (int i = 0; i < 3; i++) {
    v[i] = xr[lane + i * 64];
    s += (v[i].x + v[i].y) + (v[i].z + v[i].w);
  }
#pragma unroll
  for (int o = 32; o; o >>= 1) s += __shfl_xor(s, o);
  float mean = s * (1.f / 768.f);
  float var = 0.f;
#pragma unroll
  for (int i = 0; i < 3; i++) {
    float d0 = v[i].x - mean, d1 = v[i].y - mean;
    float d2 = v[i].z - mean, d3 = v[i].w - mean;
    var += (d0 * d0 + d1 * d1) + (d2 * d2 + d3 * d3);
  }
#pragma unroll
  for (int o = 32; o; o >>= 1) var += __shfl_xor(var, o);
  float rs = rsqrtf(var * (1.f / 768.f) + 1e-5f);
  const float4* w4 = (const float4*)w;
  const float4* b4 = (const float4*)b;
  bf16* orow = outp + (size_t)row * 768;
#pragma unroll
  for (int i = 0; i < 3; i++) {
    int e4 = lane + i * 64;
    float4 wv = w4[e4], bv = b4[e4];
    union { bf16 h; short s; } c0, c1, c2, c3;
    c0.h = __float2bfloat16((v[i].x - mean) * rs * wv.x + bv.x);
    c1.h = __float2bfloat16((v[i].y - mean) * rs * wv.y + bv.y);
    c2.h = __float2bfloat16((v[i].z - mean) * rs * wv.z + bv.z);
    c3.h = __float2bfloat16((v[i].w - mean) * rs * wv.w + bv.w);
    short4 o4 = make_short4(c0.s, c1.s, c2.s, c3.s);
    *(short4*)(orow + e4 * 4) = o4;
  }
}

// ---------------- MFMA flash attention --------------------------------------
__device__ __forceinline__ unsigned pkbf(float a, float b) {
  union { bf16 h; unsigned short u; } ua, ub;
  ua.h = __float2bfloat16(a); ub.h = __float2bfloat16(b);
  return ((unsigned)ub.u << 16) | (unsigned)ua.u;
}

__global__ __launch_bounds__(256) void attn2_k(const bf16* __restrict__ qkvb,
                                               const bf16* __restrict__ vtg,
                                               const float* __restrict__ biasT,
                                               bf16* __restrict__ outp) {
  __shared__ bf16 Ks[NPAD * 64];
  __shared__ bf16 Vt[64 * NPAD];
  __shared__ bf16 Ps[4][64 * 32];
  __shared__ float denl[4][64];

  const int bh = blockIdx.x;
  const int b = bh / 12, h = bh % 12;
  const int tid = threadIdx.x;
  const int wave = tid >> 6, lane = tid & 63;
  const int l15 = lane & 15, lg = lane >> 4;
  const int qbase = wave * 64;

  const bf16* vsrc = vtg + (size_t)bh * 64 * NPAD;
#pragma unroll
  for (int i = 0; i < 7; i++) {
    int c = i * 256 + tid;
    GLD(vsrc + c * 8, Vt + c * 8);
  }
#pragma unroll
  for (int i = 0; i < 7; i++) {
    int slot = i * 256 + tid;
    int r = slot >> 3, c8 = (slot & 7) * 8;
    int rg = min(r, NTOK - 1);
    short8 kv = *(const short8*)(qkvb + (size_t)(b * NTOK + rg) * 2304 + 768 + h * 64 + c8);
    int byte = (r * 128 + c8 * 2) ^ ((r & 7) << 4);
    *(short8*)((char*)Ks + byte) = kv;
  }
  short8 qf[4][2];
#pragma unroll
  for (int nf = 0; nf < 4; nf++) {
    int n = qbase + nf * 16 + l15;
    const bf16* qp = qkvb + (size_t)(b * NTOK + min(n, NTOK - 1)) * 2304 + h * 64;
    qf[nf][0] = *(const short8*)(qp + lg * 8);
    qf[nf][1] = *(const short8*)(qp + 32 + lg * 8);
  }
  __syncthreads();

  f32x4 Oacc[4][4];
#pragma unroll
  for (int i = 0; i < 4; i++)
#pragma unroll
    for (int j = 0; j < 4; j++) Oacc[i][j] = (f32x4){0.f, 0.f, 0.f, 0.f};
  float den[4] = {0.f, 0.f, 0.f, 0.f};
  const float* bT = biasT + (size_t)h * NPAD * 256;
  char* pw = (char*)&Ps[wave][0];

  for (int c = 0; c < 7; c++) {
    const int m0 = c * 32;
    f32x4 st[2][4];
#pragma unroll
    for (int mf = 0; mf < 2; mf++)
#pragma unroll
      for (int nf = 0; nf < 4; nf++) st[mf][nf] = (f32x4){0.f, 0.f, 0.f, 0.f};
#pragma unroll
    for (int kk = 0; kk < 2; kk++) {
      short8 af[2];
#pragma unroll
      for (int mf = 0; mf < 2; mf++) {
        int m = m0 + mf * 16 + l15;
        int byte = (m * 128 + kk * 64 + lg * 16) ^ ((m & 7) << 4);
        af[mf] = *(const short8*)((const char*)Ks + byte);
      }
#pragma unroll
      for (int mf = 0; mf < 2; mf++)
#pragma unroll
        for (int nf = 0; nf < 4; nf++)
          st[mf][nf] = __builtin_amdgcn_mfma_f32_16x16x32_bf16(af[mf], qf[nf][kk], st[mf][nf], 0, 0, 0);
    }
#pragma unroll
    for (int mf = 0; mf < 2; mf++) {
      int mrow = m0 + mf * 16 + lg * 4;
#pragma unroll
      for (int nf = 0; nf < 4; nf++) {
        int n = qbase + nf * 16 + l15;
        float p0 = __expf(st[mf][nf][0] * 0.125f + bT[(mrow + 0) * 256 + n]);
        float p1 = __expf(st[mf][nf][1] * 0.125f + bT[(mrow + 1) * 256 + n]);
        float p2 = __expf(st[mf][nf][2] * 0.125f + bT[(mrow + 2) * 256 + n]);
        float p3 = __expf(st[mf][nf][3] * 0.125f + bT[(mrow + 3) * 256 + n]);
        den[nf] += (p0 + p1) + (p2 + p3);
        int nl = nf * 16 + l15;
        int byte = (nl * 64 + (mf * 16 + lg * 4) * 2) ^ ((nl & 7) << 4);
        *(unsigned*)(pw + byte) = pkbf(p0, p1);
        *(unsigned*)(pw + byte + 4) = pkbf(p2, p3);
      }
    }
    short8 pa[4], vb[4];
#pragma unroll
    for (int nf = 0; nf < 4; nf++) {
      int nl = nf * 16 + l15;
      int byte = (nl * 64 + lg * 16) ^ ((nl & 7) << 4);
      pa[nf] = *(const short8*)((const char*)pw + byte);
    }
#pragma unroll
    for (int df = 0; df < 4; df++) {
      int d = df * 16 + l15;
      vb[df] = *(const short8*)(Vt + d * NPAD + m0 + lg * 8);
    }
#pragma unroll
    for (int nf = 0; nf < 4; nf++)
#pragma unroll
      for (int df = 0; df < 4; df++)
        Oacc[nf][df] = __builtin_amdgcn_mfma_f32_16x16x32_bf16(pa[nf], vb[df], Oacc[nf][df], 0, 0, 0);
  }

#pragma unroll
  for (int nf = 0; nf < 4; nf++) {
    den[nf] += __shfl_xor(den[nf], 16);
    den[nf] += __shfl_xor(den[nf], 32);
    denl[wave][nf * 16 + l15] = den[nf];
  }
  float inv[4][4];
#pragma unroll
  for (int nf = 0; nf < 4; nf++)
#pragma unroll
    for (int j = 0; j < 4; j++)
      inv[nf][j] = 1.f / denl[wave][nf * 16 + lg * 4 + j];
#pragma unroll
  for (int nf = 0; nf < 4; nf++) {
#pragma unroll
    for (int df = 0; df < 4; df++) {
#pragma unroll
      for (int j = 0; j < 4; j++) {
        int n = qbase + nf * 16 + lg * 4 + j;
        if (n < NTOK)
          outp[(size_t)(b * NTOK + n) * 768 + h * 64 + df * 16 + l15] =
              __float2bfloat16(Oacc[nf][df][j] * inv[nf][j]);
      }
    }
  }
}

// ---------------- mean-pool + LayerNorm -------------------------------------
__device__ __forceinline__ float block_sum(float v, float* sm4) {
#pragma unroll
  for (int o = 32; o; o >>= 1) v += __shfl_down(v, o);
  __syncthreads();
  if ((threadIdx.x & 63) == 0) sm4[threadIdx.x >> 6] = v;
  __syncthreads();
  return sm4[0] + sm4[1] + sm4[2] + sm4[3];
}

__global__ __launch_bounds__(256) void pool_ln_k(const float* __restrict__ h,
                                                 const float* __restrict__ w,
                                                 const float* __restrict__ bi,
                                                 float* __restrict__ feat) {
  __shared__ float sm4[4];
  int b = blockIdx.x, tid = threadIdx.x;
  float vals[3];
  float local = 0.f;
#pragma unroll
  for (int j = 0; j < 3; j++) {
    int e = tid + j * 256;
    float s = 0.f;
    for (int nn = 1; nn < 197; nn++) s += h[((size_t)(b * 197 + nn)) * 768 + e];
    s *= (1.f / 196.f);
    vals[j] = s;
    local += s;
  }
  float tot = block_sum(local, sm4);
  float mean = tot * (1.f / 768.f);
  float lv = 0.f;
#pragma unroll
  for (int j = 0; j < 3; j++) { float d = vals[j] - mean; lv += d * d; }
  float vtot = block_sum(lv, sm4);
  float rs = rsqrtf(vtot * (1.f / 768.f) + 1e-5f);
#pragma unroll
  for (int j = 0; j < 3; j++) {
    int e = tid + j * 256;
    feat[(size_t)b * 768 + e] = (vals[j] - mean) * rs * w[e] + bi[e];
  }
}

// ---------------- small fp32 GEMM for the head ------------------------------
__global__ __launch_bounds__(256) void head_k(const float* __restrict__ A,
                                              const float* __restrict__ W,
                                              const float* __restrict__ bias,
                                              float* __restrict__ C,
                                              int M, int Nn, int K) {
  __shared__ float As[16][64 + 4];
  __shared__ float Bs[16][64 + 4];
  int tid = threadIdx.x;
  int tx = tid & 15, ty = tid >> 4;
  int row0 = blockIdx.x * 64, n0 = blockIdx.y * 64;
  int lrow = tid >> 2;
  int kq = (tid & 3) * 4;
  float acc[4][4];
#pragma unroll
  for (int i = 0; i < 4; i++)
#pragma unroll
    for (int j = 0; j < 4; j++) acc[i][j] = 0.f;
  for (int k0 = 0; k0 < K; k0 += 16) {
    float4 av = make_float4(0.f, 0.f, 0.f, 0.f);
    if (row0 + lrow < M) av = *(const float4*)&A[(size_t)(row0 + lrow) * K + k0 + kq];
    As[kq + 0][lrow] = av.x; As[kq + 1][lrow] = av.y;
    As[kq + 2][lrow] = av.z; As[kq + 3][lrow] = av.w;
    float4 bv = make_float4(0.f, 0.f, 0.f, 0.f);
    if (n0 + lrow < Nn) bv = *(const float4*)&W[(size_t)(n0 + lrow) * K + k0 + kq];
    Bs[kq + 0][lrow] = bv.x; Bs[kq + 1][lrow] = bv.y;
    Bs[kq + 2][lrow] = bv.z; Bs[kq + 3][lrow] = bv.w;
    __syncthreads();
#pragma unroll
    for (int kk = 0; kk < 16; kk++) {
      float4 a = *(const float4*)&As[kk][ty * 4];
      float4 b = *(const float4*)&Bs[kk][tx * 4];
      float aa[4] = {a.x, a.y, a.z, a.w};
      float bb[4] = {b.x, b.y, b.z, b.w};
#pragma unroll
      for (int i = 0; i < 4; i++)
#pragma unroll
        for (int j = 0; j < 4; j++) acc[i][j] = fmaf(aa[i], bb[j], acc[i][j]);
    }
    __syncthreads();
  }
#pragma unroll
  for (int i = 0; i < 4; i++) {
    int gr = row0 + ty * 4 + i;
    if (gr >= M) continue;
#pragma unroll
    for (int j = 0; j < 4; j++) {
      int gc = n0 + tx * 4 + j;
      if (gc >= Nn) continue;
      C[(size_t)gr * Nn + gc] = acc[i][j] + bias[gc];
    }
  }
}

// ============================================================================
extern "C" void kernel_launch(void* const* d_in, const int* in_sizes, int n_in,
                              void* d_out, int out_size, void* d_ws, size_t ws_size,
                              hipStream_t stream) {
  const float* x       = (const float*)d_in[0];
  const float* patch_w = (const float*)d_in[1];
  const float* patch_b = (const float*)d_in[2];
  const float* cls_tok = (const float*)d_in[3];
  const float* ln1_w   = (const float*)d_in[4];
  const float* ln1_b   = (const float*)d_in[5];
  const float* qkv_w   = (const float*)d_in[6];
  const float* q_bias  = (const float*)d_in[7];
  const float* v_bias  = (const float*)d_in[8];
  const float* rel_tab = (const float*)d_in[9];
  const float* proj_w  = (const float*)d_in[10];
  const float* proj_b  = (const float*)d_in[11];
  const float* ln2_w   = (const float*)d_in[12];
  const float* ln2_b   = (const float*)d_in[13];
  const float* fc1_w   = (const float*)d_in[14];
  const float* fc1_b   = (const float*)d_in[15];
  const float* fc2_w   = (const float*)d_in[16];
  const float* fc2_b   = (const float*)d_in[17];
  const float* fcn_w   = (const float*)d_in[18];
  const float* fcn_b   = (const float*)d_in[19];
  const float* head_w  = (const float*)d_in[20];
  const float* head_b  = (const float*)d_in[21];
  float* outp = (float*)d_out;

  char* wsb = (char*)d_ws;
  float* h    = (float*)wsb;  wsb += 19365888;   // [6304][768] f32
  bf16* bigb  = (bf16*)wsb;   wsb += 29048832;   // [6304][2304]
  bf16* yb    = (bf16*)wsb;   wsb += 9830400;    // [6400][768]
  bf16* hid   = (bf16*)wsb;   wsb += 39321600;   // [6400][3072]
  bf16* wl    = (bf16*)wsb;   wsb += 14155776;
  bf16* vt_g  = (bf16*)wsb;   wsb += 11010048;   // [32][12][64][224]
  float* biasT = (float*)wsb; wsb += 2752512;    // [12][224][256] f32
  float* feat = (float*)wsb;

  const int M = 6304;

  vtz_k<<<2688, 256, 0, stream>>>(vt_g);
  patchify_k<<<(6272 * 768 + 255) / 256, 256, 0, stream>>>(x, hid);
  cvt_k<<<(589824 / 8 + 255) / 256, 256, 0, stream>>>(patch_w, wl, 589824 / 8);
  mm128_k<0><<<dim3(49, 6), 256, 0, stream>>>(
      hid, wl, patch_b, nullptr, h, 6272, 768, 768);
  clsfill_k<<<(32 * 768 + 255) / 256, 256, 0, stream>>>(cls_tok, h);

  for (int d = 0; d < 12; d++) {
    prep_k<<<6144, 256, 0, stream>>>(qkv_w, proj_w, fc1_w, fc2_w, rel_tab,
                                     wl, biasT, d);
    ln_k<<<dim3((M + 3) / 4), dim3(64, 4), 0, stream>>>(h, yb, ln1_w + d * 768, ln1_b + d * 768, M);
    mm256_k<1><<<dim3(25, 18), 512, 0, stream>>>(
        yb, wl, q_bias + d * 768, v_bias + d * 768, bigb, vt_g, M, 2304, 768);
    attn2_k<<<32 * NHEAD, 256, 0, stream>>>(bigb, vt_g, biasT, yb);
    mm128_k<2><<<dim3(50, 6), 256, 0, stream>>>(
        yb, wl + O_PROJ, proj_b + d * 768, h, h, M, 768, 768);
    ln_k<<<dim3((M + 3) / 4), dim3(64, 4), 0, stream>>>(h, yb, ln2_w + d * 768, ln2_b + d * 768, M);
    mm256_k<3><<<dim3(25, 24), 512, 0, stream>>>(
        yb, wl + O_FC1, fc1_b + d * 3072, nullptr, hid, nullptr, M, 3072, 768);
    mm128_k<2><<<dim3(50, 6), 256, 0, stream>>>(
        hid, wl + O_FC2, fc2_b + d * 768, h, h, M, 768, 3072);
  }

  pool_ln_k<<<32, 256, 0, stream>>>(h, fcn_w, fcn_b, feat);
  {
    dim3 g(1, (1000 + 63) / 64);
    head_k<<<g, 256, 0, stream>>>(feat, head_w, head_b, outp, 32, 1000, 768);
  }
}

// Round 13
// 3301.008 us; speedup vs baseline: 1.0328x; 1.0328x over previous
//
#include <hip/hip_runtime.h>
#include <hip/hip_bf16.h>
#include <math.h>

// ============================================================================
// BEiT ViT-B/16 forward — round 13: verbatim restore of the round-9 champion
// (3,296 us): r6 3-ring counted-vmcnt MFMA GEMMs (mm256 loop vmcnt(2),
// mm128 loop vmcnt(3)), fc2 de-split, fused per-layer prep, vectorized LN,
// MFMA flash attention.
// ============================================================================

typedef __hip_bfloat16 bf16;
using short8 = __attribute__((ext_vector_type(8))) short;
using f32x4  = __attribute__((ext_vector_type(4))) float;

#define NTOK 197
#define NHEAD 12
#define NPAD 224

#define S_QKV  1769472
#define S_PROJ 589824
#define S_FC   2359296
#define O_PROJ 1769472
#define O_FC1  2359296
#define O_FC2  4718592
#define W_TOT  7077888

#define GLD(gp, lp) __builtin_amdgcn_global_load_lds( \
    (const unsigned int __attribute__((address_space(1)))*)(gp), \
    (unsigned int __attribute__((address_space(3)))*)(lp), 16, 0, 0)

// ---------------- fp32 -> bf16 convert (patch_w) -----------------------------
__global__ __launch_bounds__(256) void cvt_k(const float* __restrict__ src,
                                             bf16* __restrict__ dst, int n8) {
  int t = blockIdx.x * 256 + threadIdx.x;
  if (t >= n8) return;
  size_t i = (size_t)t * 8;
  float4 a = *(const float4*)(src + i);
  float4 b = *(const float4*)(src + i + 4);
  union { short8 v; bf16 e[8]; } u;
  u.e[0] = __float2bfloat16(a.x); u.e[1] = __float2bfloat16(a.y);
  u.e[2] = __float2bfloat16(a.z); u.e[3] = __float2bfloat16(a.w);
  u.e[4] = __float2bfloat16(b.x); u.e[5] = __float2bfloat16(b.y);
  u.e[6] = __float2bfloat16(b.z); u.e[7] = __float2bfloat16(b.w);
  *(short8*)(dst + i) = u.v;
}

// ---------------- BEiT relative-position index -------------------------------
__device__ __forceinline__ int ridx(int n, int m) {
  if (n == 0) return (m == 0) ? 731 : 729;
  if (m == 0) return 730;
  int nh = (n - 1) / 14, nw = (n - 1) % 14;
  int mh = (m - 1) / 14, mw = (m - 1) % 14;
  return (nh - mh + 13) * 27 + (nw - mw + 13);
}

// ---------------- fused per-layer prep: weight cvt + bias table --------------
__global__ __launch_bounds__(256) void prep_k(
    const float* __restrict__ qkvw, const float* __restrict__ projw,
    const float* __restrict__ fc1w, const float* __restrict__ fc2w,
    const float* __restrict__ rel, bf16* __restrict__ wl,
    float* __restrict__ biasT, int d) {
  int blk = blockIdx.x;
  if (blk < 3456) {
    size_t i = ((size_t)blk * 256 + threadIdx.x) * 8;
    const float* src;
    if (i < O_PROJ)      src = qkvw + (size_t)d * S_QKV + i;
    else if (i < O_FC1)  src = projw + (size_t)d * S_PROJ + (i - O_PROJ);
    else if (i < O_FC2)  src = fc1w + (size_t)d * S_FC + (i - O_FC1);
    else                 src = fc2w + (size_t)d * S_FC + (i - O_FC2);
    float4 a = *(const float4*)src;
    float4 b = *(const float4*)(src + 4);
    union { short8 v; bf16 e[8]; } u;
    u.e[0] = __float2bfloat16(a.x); u.e[1] = __float2bfloat16(a.y);
    u.e[2] = __float2bfloat16(a.z); u.e[3] = __float2bfloat16(a.w);
    u.e[4] = __float2bfloat16(b.x); u.e[5] = __float2bfloat16(b.y);
    u.e[6] = __float2bfloat16(b.z); u.e[7] = __float2bfloat16(b.w);
    *(short8*)(wl + i) = u.v;
  } else {
    int idx = (blk - 3456) * 256 + threadIdx.x;
    int h = idx / (NPAD * 256);
    int rem = idx % (NPAD * 256);
    int m = rem / 256, n = rem % 256;
    float v;
    if (m >= NTOK) {
      v = -1e30f;
    } else {
      int nn = min(n, NTOK - 1);
      v = rel[((size_t)d * 732 + ridx(nn, m)) * 12 + h];
    }
    biasT[idx] = v;
  }
}

// ---------------- patchify ---------------------------------------------------
__global__ __launch_bounds__(256) void patchify_k(const float* __restrict__ x,
                                                  bf16* __restrict__ patches) {
  int o = blockIdx.x * 256 + threadIdx.x;
  if (o >= 6272 * 768) return;
  int row = o / 768, col = o % 768;
  int b = row / 196, g = row % 196;
  int gh = g / 14, gw = g % 14;
  int c = col / 256, r = col % 256;
  int ph = r / 16, pw = r % 16;
  patches[o] = __float2bfloat16(
      x[(((size_t)b * 3 + c) * 224 + gh * 16 + ph) * 224 + gw * 16 + pw]);
}

// ---------------- cls token fill ---------------------------------------------
__global__ __launch_bounds__(256) void clsfill_k(const float* __restrict__ cls,
                                                 float* __restrict__ h) {
  int i = blockIdx.x * 256 + threadIdx.x;
  if (i >= 32 * 768) return;
  int b = i / 768, e = i % 768;
  h[((size_t)b * 197) * 768 + e] = cls[e];
}

// ---------------- zero vt ----------------------------------------------------
__global__ __launch_bounds__(256) void vtz_k(bf16* __restrict__ vt) {
  int i = blockIdx.x * 256 + threadIdx.x;
  if (i >= 32 * 12 * 64 * NPAD / 8) return;
  *(short8*)(vt + (size_t)i * 8) = (short8){0,0,0,0,0,0,0,0};
}

// ============================================================================
// mm256: 3-ring counted-vmcnt MFMA GEMM, BM=256 x BN=128, BK=32, 512 thr /
// 8 waves (4m x 2n), per-wave 64x64. LDS = 3 x 24KB = 72KB -> 2 blocks/CU.
// r6-proven schedule: prologue vmcnt(3), loop vmcnt(2).
// EPI: 1=qkv (split bias, Q/K->bf16, V->vt), 3=fc1 (bias+gelu->bf16).
// ============================================================================
template <int EPI>
__global__ __launch_bounds__(512, 4) void mm256_k(
    const bf16* __restrict__ A, const bf16* __restrict__ W,
    const float* __restrict__ bias, const float* __restrict__ bias2,
    void* __restrict__ Cout, bf16* __restrict__ vtg,
    int M, int Nn, int K) {
  constexpr int BUFSZ = 24576;
  __shared__ __attribute__((aligned(16))) char lds[3 * BUFSZ];
  const int tid = threadIdx.x;
  const int lane = tid & 63, wave = tid >> 6;
  const int wr = wave >> 1, wc = wave & 1;
  const int l15 = lane & 15, lg = lane >> 4;
  const int row0 = blockIdx.x * 256, n0 = blockIdx.y * 128;
  const int nt = K >> 5, ntm1 = nt - 1;

  const bf16 *gA0, *gA1, *gB0;
  int dA0, dA1, dB0;
  {
    int s = tid * 16;
    int r = s >> 6, cl = ((s >> 4) & 3) ^ ((r >> 1) & 3);
    gA0 = A + (size_t)(row0 + r) * K + cl * 8;  dA0 = s;
    s = 8192 + tid * 16;
    r = s >> 6; cl = ((s >> 4) & 3) ^ ((r >> 1) & 3);
    gA1 = A + (size_t)(row0 + r) * K + cl * 8;  dA1 = s;
    s = tid * 16;
    r = s >> 6; cl = ((s >> 4) & 3) ^ ((r >> 1) & 3);
    gB0 = W + (size_t)(n0 + r) * K + cl * 8;    dB0 = 16384 + s;
  }
  int oA[4], oB[4];
#pragma unroll
  for (int m = 0; m < 4; m++) {
    int r = wr * 64 + m * 16 + l15;
    oA[m] = (r << 6) | ((lg ^ ((r >> 1) & 3)) << 4);
  }
#pragma unroll
  for (int n = 0; n < 4; n++) {
    int r = wc * 64 + n * 16 + l15;
    oB[n] = 16384 + ((r << 6) | ((lg ^ ((r >> 1) & 3)) << 4));
  }

  f32x4 acc[4][4];
#pragma unroll
  for (int m = 0; m < 4; m++)
#pragma unroll
    for (int n = 0; n < 4; n++) acc[m][n] = (f32x4){0.f, 0.f, 0.f, 0.f};

  GLD(gA0, lds + dA0); GLD(gA1, lds + dA1); GLD(gB0, lds + dB0);
  GLD(gA0 + 32, lds + BUFSZ + dA0); GLD(gA1 + 32, lds + BUFSZ + dA1);
  GLD(gB0 + 32, lds + BUFSZ + dB0);
  asm volatile("s_waitcnt vmcnt(3)" ::: "memory");
  __builtin_amdgcn_s_barrier();
  __builtin_amdgcn_sched_barrier(0);

#define MB(RB, WB, tt)                                                        \
  {                                                                           \
    int ks = (tt) + 2; if (ks > ntm1) ks = ntm1; ks <<= 5;                    \
    char* wb = lds + (WB) * BUFSZ;                                            \
    GLD(gA0 + ks, wb + dA0); GLD(gA1 + ks, wb + dA1);                         \
    GLD(gB0 + ks, wb + dB0);                                                  \
    const char* rb = lds + (RB) * BUFSZ;                                      \
    short8 a[4], b[4];                                                        \
    _Pragma("unroll") for (int m = 0; m < 4; m++)                             \
      a[m] = *(const short8*)(rb + oA[m]);                                    \
    _Pragma("unroll") for (int n = 0; n < 4; n++)                             \
      b[n] = *(const short8*)(rb + oB[n]);                                    \
    __builtin_amdgcn_s_setprio(1);                                            \
    _Pragma("unroll") for (int m = 0; m < 4; m++)                             \
      _Pragma("unroll") for (int n = 0; n < 4; n++)                           \
        acc[m][n] = __builtin_amdgcn_mfma_f32_16x16x32_bf16(a[m], b[n], acc[m][n], 0, 0, 0); \
    __builtin_amdgcn_s_setprio(0);                                            \
    __builtin_amdgcn_sched_barrier(0);                                        \
    asm volatile("s_waitcnt vmcnt(2)" ::: "memory");                          \
    __builtin_amdgcn_s_barrier();                                             \
    __builtin_amdgcn_sched_barrier(0);                                        \
  }

  for (int t = 0; t < nt; t += 3) {  // nt % 3 == 0
    MB(0, 2, t); MB(1, 0, t + 1); MB(2, 1, t + 2);
  }
#undef MB
  asm volatile("s_waitcnt vmcnt(0)" ::: "memory");

#pragma unroll
  for (int m = 0; m < 4; m++) {
    const int rbase = row0 + wr * 64 + m * 16 + lg * 4;
#pragma unroll
    for (int n = 0; n < 4; n++) {
      const int gc = n0 + wc * 64 + n * 16 + l15;
      f32x4 v = acc[m][n];
#pragma unroll
      for (int j = 0; j < 4; j++) {
        int gr = rbase + j;
        if (gr >= M) continue;
        float val = v[j];
        if (EPI == 1) {
          if (gc < 768) val += bias[gc];
          else if (gc >= 1536) val += bias2[gc - 1536];
          if (gc >= 1536) {
            int ob = gr / 197, nn = gr - ob * 197, hd = gc - 1536;
            vtg[(((size_t)ob * 12 + (hd >> 6)) * 64 + (hd & 63)) * NPAD + nn] =
                __float2bfloat16(val);
          } else {
            ((bf16*)Cout)[(size_t)gr * Nn + gc] = __float2bfloat16(val);
          }
        } else {  // EPI == 3
          val += bias[gc];
          val = 0.5f * val * (1.f + erff(val * 0.70710678118654752f));
          ((bf16*)Cout)[(size_t)gr * Nn + gc] = __float2bfloat16(val);
        }
      }
    }
  }
}

// ============================================================================
// mm128: 3-ring counted-vmcnt, BM=BN=128, BK=32, 256 thr / 4 waves (2x2),
// per-wave 64x64. LDS = 48KB -> 3 blocks/CU. r6 schedule: prologue vmcnt(4),
// loop vmcnt(3). EPI: 0=patch (bias, f32, remap), 2=bias+residual (f32).
// ============================================================================
template <int EPI>
__global__ __launch_bounds__(256, 3) void mm128_k(
    const bf16* __restrict__ A, const bf16* __restrict__ W,
    const float* __restrict__ bias, const float* __restrict__ Res,
    void* __restrict__ Cout, int M, int Nn, int K) {
  constexpr int BUFSZ = 16384;
  __shared__ __attribute__((aligned(16))) char lds[3 * BUFSZ];
  const int tid = threadIdx.x;
  const int lane = tid & 63, wave = tid >> 6;
  const int wr = wave >> 1, wc = wave & 1;
  const int l15 = lane & 15, lg = lane >> 4;
  const int row0 = blockIdx.x * 128, n0 = blockIdx.y * 128;
  const int nt = K >> 5, ntm1 = nt - 1;

  const bf16 *gA0, *gA1, *gB0, *gB1;
  int dA0, dA1, dB0, dB1;
  {
    int s = tid * 16;
    int r = s >> 6, cl = ((s >> 4) & 3) ^ ((r >> 1) & 3);
    gA0 = A + (size_t)(row0 + r) * K + cl * 8;  dA0 = s;
    s = 4096 + tid * 16;
    r = s >> 6; cl = ((s >> 4) & 3) ^ ((r >> 1) & 3);
    gA1 = A + (size_t)(row0 + r) * K + cl * 8;  dA1 = s;
    s = tid * 16;
    r = s >> 6; cl = ((s >> 4) & 3) ^ ((r >> 1) & 3);
    gB0 = W + (size_t)(n0 + r) * K + cl * 8;    dB0 = 8192 + s;
    s = 4096 + tid * 16;
    r = s >> 6; cl = ((s >> 4) & 3) ^ ((r >> 1) & 3);
    gB1 = W + (size_t)(n0 + r) * K + cl * 8;    dB1 = 8192 + s;
  }
  int oA[4], oB[4];
#pragma unroll
  for (int m = 0; m < 4; m++) {
    int r = wr * 64 + m * 16 + l15;
    oA[m] = (r << 6) | ((lg ^ ((r >> 1) & 3)) << 4);
  }
#pragma unroll
  for (int n = 0; n < 4; n++) {
    int r = wc * 64 + n * 16 + l15;
    oB[n] = 8192 + ((r << 6) | ((lg ^ ((r >> 1) & 3)) << 4));
  }

  f32x4 acc[4][4];
#pragma unroll
  for (int m = 0; m < 4; m++)
#pragma unroll
    for (int n = 0; n < 4; n++) acc[m][n] = (f32x4){0.f, 0.f, 0.f, 0.f};

  GLD(gA0, lds + dA0); GLD(gA1, lds + dA1);
  GLD(gB0, lds + dB0); GLD(gB1, lds + dB1);
  GLD(gA0 + 32, lds + BUFSZ + dA0); GLD(gA1 + 32, lds + BUFSZ + dA1);
  GLD(gB0 + 32, lds + BUFSZ + dB0); GLD(gB1 + 32, lds + BUFSZ + dB1);
  asm volatile("s_waitcnt vmcnt(4)" ::: "memory");
  __builtin_amdgcn_s_barrier();
  __builtin_amdgcn_sched_barrier(0);

#define MB(RB, WB, tt)                                                        \
  {                                                                           \
    int ks = (tt) + 2; if (ks > ntm1) ks = ntm1; ks <<= 5;                    \
    char* wb = lds + (WB) * BUFSZ;                                            \
    GLD(gA0 + ks, wb + dA0); GLD(gA1 + ks, wb + dA1);                         \
    GLD(gB0 + ks, wb + dB0); GLD(gB1 + ks, wb + dB1);                         \
    const char* rb = lds + (RB) * BUFSZ;                                      \
    short8 a[4], b[4];                                                        \
    _Pragma("unroll") for (int m = 0; m < 4; m++)                             \
      a[m] = *(const short8*)(rb + oA[m]);                                    \
    _Pragma("unroll") for (int n = 0; n < 4; n++)                             \
      b[n] = *(const short8*)(rb + oB[n]);                                    \
    __builtin_amdgcn_s_setprio(1);                                            \
    _Pragma("unroll") for (int m = 0; m < 4; m++)                             \
      _Pragma("unroll") for (int n = 0; n < 4; n++)                           \
        acc[m][n] = __builtin_amdgcn_mfma_f32_16x16x32_bf16(a[m], b[n], acc[m][n], 0, 0, 0); \
    __builtin_amdgcn_s_setprio(0);                                            \
    __builtin_amdgcn_sched_barrier(0);                                        \
    asm volatile("s_waitcnt vmcnt(3)" ::: "memory");                          \
    __builtin_amdgcn_s_barrier();                                             \
    __builtin_amdgcn_sched_barrier(0);                                        \
  }

  for (int t = 0; t < nt; t += 3) {  // nt % 3 == 0
    MB(0, 2, t); MB(1, 0, t + 1); MB(2, 1, t + 2);
  }
#undef MB
  asm volatile("s_waitcnt vmcnt(0)" ::: "memory");

#pragma unroll
  for (int m = 0; m < 4; m++) {
    const int rbase = row0 + wr * 64 + m * 16 + lg * 4;
#pragma unroll
    for (int n = 0; n < 4; n++) {
      const int gc = n0 + wc * 64 + n * 16 + l15;
      f32x4 v = acc[m][n];
#pragma unroll
      for (int j = 0; j < 4; j++) {
        int gr = rbase + j;
        if (gr >= M) continue;
        float val = v[j] + bias[gc];
        if (EPI == 2) val += Res[(size_t)gr * Nn + gc];
        int orow = (EPI == 0) ? (gr + gr / 196 + 1) : gr;
        ((float*)Cout)[(size_t)orow * Nn + gc] = val;
      }
    }
  }
}

// ---------------- LayerNorm (768), fp32 in -> bf16 out, vectorized ----------
__global__ __launch_bounds__(256) void ln_k(const float* __restrict__ in,
                                            bf16* __restrict__ outp,
                                            const float* __restrict__ w,
                                            const float* __restrict__ b,
                                            int rows) {
  int row = blockIdx.x * 4 + threadIdx.y;
  if (row >= rows) return;
  int lane = threadIdx.x;
  const float4* xr = (const float4*)(in + (size_t)row * 768);
  float4 v[3];
  float s = 0.f;
#pragma unroll
  for (int i = 0; i < 3; i++) {
    v[i] = xr[lane + i * 64];
    s += (v[i].x + v[i].y) + (v[i].z + v[i].w);
  }
#pragma unroll
  for (int o = 32; o; o >>= 1) s += __shfl_xor(s, o);
  float mean = s * (1.f / 768.f);
  float var = 0.f;
#pragma unroll
  for (int i = 0; i < 3; i++) {
    float d0 = v[i].x - mean, d1 = v[i].y - mean;
    float d2 = v[i].z - mean, d3 = v[i].w - mean;
    var += (d0 * d0 + d1 * d1) + (d2 * d2 + d3 * d3);
  }
#pragma unroll
  for (int o = 32; o; o >>= 1) var += __shfl_xor(var, o);
  float rs = rsqrtf(var * (1.f / 768.f) + 1e-5f);
  const float4* w4 = (const float4*)w;
  const float4* b4 = (const float4*)b;
  bf16* orow = outp + (size_t)row * 768;
#pragma unroll
  for (int i = 0; i < 3; i++) {
    int e4 = lane + i * 64;
    float4 wv = w4[e4], bv = b4[e4];
    union { bf16 h; short s; } c0, c1, c2, c3;
    c0.h = __float2bfloat16((v[i].x - mean) * rs * wv.x + bv.x);
    c1.h = __float2bfloat16((v[i].y - mean) * rs * wv.y + bv.y);
    c2.h = __float2bfloat16((v[i].z - mean) * rs * wv.z + bv.z);
    c3.h = __float2bfloat16((v[i].w - mean) * rs * wv.w + bv.w);
    short4 o4 = make_short4(c0.s, c1.s, c2.s, c3.s);
    *(short4*)(orow + e4 * 4) = o4;
  }
}

// ---------------- MFMA flash attention --------------------------------------
__device__ __forceinline__ unsigned pkbf(float a, float b) {
  union { bf16 h; unsigned short u; } ua, ub;
  ua.h = __float2bfloat16(a); ub.h = __float2bfloat16(b);
  return ((unsigned)ub.u << 16) | (unsigned)ua.u;
}

__global__ __launch_bounds__(256) void attn2_k(const bf16* __restrict__ qkvb,
                                               const bf16* __restrict__ vtg,
                                               const float* __restrict__ biasT,
                                               bf16* __restrict__ outp) {
  __shared__ bf16 Ks[NPAD * 64];
  __shared__ bf16 Vt[64 * NPAD];
  __shared__ bf16 Ps[4][64 * 32];
  __shared__ float denl[4][64];

  const int bh = blockIdx.x;
  const int b = bh / 12, h = bh % 12;
  const int tid = threadIdx.x;
  const int wave = tid >> 6, lane = tid & 63;
  const int l15 = lane & 15, lg = lane >> 4;
  const int qbase = wave * 64;

  const bf16* vsrc = vtg + (size_t)bh * 64 * NPAD;
#pragma unroll
  for (int i = 0; i < 7; i++) {
    int c = i * 256 + tid;
    GLD(vsrc + c * 8, Vt + c * 8);
  }
#pragma unroll
  for (int i = 0; i < 7; i++) {
    int slot = i * 256 + tid;
    int r = slot >> 3, c8 = (slot & 7) * 8;
    int rg = min(r, NTOK - 1);
    short8 kv = *(const short8*)(qkvb + (size_t)(b * NTOK + rg) * 2304 + 768 + h * 64 + c8);
    int byte = (r * 128 + c8 * 2) ^ ((r & 7) << 4);
    *(short8*)((char*)Ks + byte) = kv;
  }
  short8 qf[4][2];
#pragma unroll
  for (int nf = 0; nf < 4; nf++) {
    int n = qbase + nf * 16 + l15;
    const bf16* qp = qkvb + (size_t)(b * NTOK + min(n, NTOK - 1)) * 2304 + h * 64;
    qf[nf][0] = *(const short8*)(qp + lg * 8);
    qf[nf][1] = *(const short8*)(qp + 32 + lg * 8);
  }
  __syncthreads();

  f32x4 Oacc[4][4];
#pragma unroll
  for (int i = 0; i < 4; i++)
#pragma unroll
    for (int j = 0; j < 4; j++) Oacc[i][j] = (f32x4){0.f, 0.f, 0.f, 0.f};
  float den[4] = {0.f, 0.f, 0.f, 0.f};
  const float* bT = biasT + (size_t)h * NPAD * 256;
  char* pw = (char*)&Ps[wave][0];

  for (int c = 0; c < 7; c++) {
    const int m0 = c * 32;
    f32x4 st[2][4];
#pragma unroll
    for (int mf = 0; mf < 2; mf++)
#pragma unroll
      for (int nf = 0; nf < 4; nf++) st[mf][nf] = (f32x4){0.f, 0.f, 0.f, 0.f};
#pragma unroll
    for (int kk = 0; kk < 2; kk++) {
      short8 af[2];
#pragma unroll
      for (int mf = 0; mf < 2; mf++) {
        int m = m0 + mf * 16 + l15;
        int byte = (m * 128 + kk * 64 + lg * 16) ^ ((m & 7) << 4);
        af[mf] = *(const short8*)((const char*)Ks + byte);
      }
#pragma unroll
      for (int mf = 0; mf < 2; mf++)
#pragma unroll
        for (int nf = 0; nf < 4; nf++)
          st[mf][nf] = __builtin_amdgcn_mfma_f32_16x16x32_bf16(af[mf], qf[nf][kk], st[mf][nf], 0, 0, 0);
    }
#pragma unroll
    for (int mf = 0; mf < 2; mf++) {
      int mrow = m0 + mf * 16 + lg * 4;
#pragma unroll
      for (int nf = 0; nf < 4; nf++) {
        int n = qbase + nf * 16 + l15;
        float p0 = __expf(st[mf][nf][0] * 0.125f + bT[(mrow + 0) * 256 + n]);
        float p1 = __expf(st[mf][nf][1] * 0.125f + bT[(mrow + 1) * 256 + n]);
        float p2 = __expf(st[mf][nf][2] * 0.125f + bT[(mrow + 2) * 256 + n]);
        float p3 = __expf(st[mf][nf][3] * 0.125f + bT[(mrow + 3) * 256 + n]);
        den[nf] += (p0 + p1) + (p2 + p3);
        int nl = nf * 16 + l15;
        int byte = (nl * 64 + (mf * 16 + lg * 4) * 2) ^ ((nl & 7) << 4);
        *(unsigned*)(pw + byte) = pkbf(p0, p1);
        *(unsigned*)(pw + byte + 4) = pkbf(p2, p3);
      }
    }
    short8 pa[4], vb[4];
#pragma unroll
    for (int nf = 0; nf < 4; nf++) {
      int nl = nf * 16 + l15;
      int byte = (nl * 64 + lg * 16) ^ ((nl & 7) << 4);
      pa[nf] = *(const short8*)((const char*)pw + byte);
    }
#pragma unroll
    for (int df = 0; df < 4; df++) {
      int d = df * 16 + l15;
      vb[df] = *(const short8*)(Vt + d * NPAD + m0 + lg * 8);
    }
#pragma unroll
    for (int nf = 0; nf < 4; nf++)
#pragma unroll
      for (int df = 0; df < 4; df++)
        Oacc[nf][df] = __builtin_amdgcn_mfma_f32_16x16x32_bf16(pa[nf], vb[df], Oacc[nf][df], 0, 0, 0);
  }

#pragma unroll
  for (int nf = 0; nf < 4; nf++) {
    den[nf] += __shfl_xor(den[nf], 16);
    den[nf] += __shfl_xor(den[nf], 32);
    denl[wave][nf * 16 + l15] = den[nf];
  }
  float inv[4][4];
#pragma unroll
  for (int nf = 0; nf < 4; nf++)
#pragma unroll
    for (int j = 0; j < 4; j++)
      inv[nf][j] = 1.f / denl[wave][nf * 16 + lg * 4 + j];
#pragma unroll
  for (int nf = 0; nf < 4; nf++) {
#pragma unroll
    for (int df = 0; df < 4; df++) {
#pragma unroll
      for (int j = 0; j < 4; j++) {
        int n = qbase + nf * 16 + lg * 4 + j;
        if (n < NTOK)
          outp[(size_t)(b * NTOK + n) * 768 + h * 64 + df * 16 + l15] =
              __float2bfloat16(Oacc[nf][df][j] * inv[nf][j]);
      }
    }
  }
}

// ---------------- mean-pool + LayerNorm -------------------------------------
__device__ __forceinline__ float block_sum(float v, float* sm4) {
#pragma unroll
  for (int o = 32; o; o >>= 1) v += __shfl_down(v, o);
  __syncthreads();
  if ((threadIdx.x & 63) == 0) sm4[threadIdx.x >> 6] = v;
  __syncthreads();
  return sm4[0] + sm4[1] + sm4[2] + sm4[3];
}

__global__ __launch_bounds__(256) void pool_ln_k(const float* __restrict__ h,
                                                 const float* __restrict__ w,
                                                 const float* __restrict__ bi,
                                                 float* __restrict__ feat) {
  __shared__ float sm4[4];
  int b = blockIdx.x, tid = threadIdx.x;
  float vals[3];
  float local = 0.f;
#pragma unroll
  for (int j = 0; j < 3; j++) {
    int e = tid + j * 256;
    float s = 0.f;
    for (int nn = 1; nn < 197; nn++) s += h[((size_t)(b * 197 + nn)) * 768 + e];
    s *= (1.f / 196.f);
    vals[j] = s;
    local += s;
  }
  float tot = block_sum(local, sm4);
  float mean = tot * (1.f / 768.f);
  float lv = 0.f;
#pragma unroll
  for (int j = 0; j < 3; j++) { float d = vals[j] - mean; lv += d * d; }
  float vtot = block_sum(lv, sm4);
  float rs = rsqrtf(vtot * (1.f / 768.f) + 1e-5f);
#pragma unroll
  for (int j = 0; j < 3; j++) {
    int e = tid + j * 256;
    feat[(size_t)b * 768 + e] = (vals[j] - mean) * rs * w[e] + bi[e];
  }
}

// ---------------- small fp32 GEMM for the head ------------------------------
__global__ __launch_bounds__(256) void head_k(const float* __restrict__ A,
                                              const float* __restrict__ W,
                                              const float* __restrict__ bias,
                                              float* __restrict__ C,
                                              int M, int Nn, int K) {
  __shared__ float As[16][64 + 4];
  __shared__ float Bs[16][64 + 4];
  int tid = threadIdx.x;
  int tx = tid & 15, ty = tid >> 4;
  int row0 = blockIdx.x * 64, n0 = blockIdx.y * 64;
  int lrow = tid >> 2;
  int kq = (tid & 3) * 4;
  float acc[4][4];
#pragma unroll
  for (int i = 0; i < 4; i++)
#pragma unroll
    for (int j = 0; j < 4; j++) acc[i][j] = 0.f;
  for (int k0 = 0; k0 < K; k0 += 16) {
    float4 av = make_float4(0.f, 0.f, 0.f, 0.f);
    if (row0 + lrow < M) av = *(const float4*)&A[(size_t)(row0 + lrow) * K + k0 + kq];
    As[kq + 0][lrow] = av.x; As[kq + 1][lrow] = av.y;
    As[kq + 2][lrow] = av.z; As[kq + 3][lrow] = av.w;
    float4 bv = make_float4(0.f, 0.f, 0.f, 0.f);
    if (n0 + lrow < Nn) bv = *(const float4*)&W[(size_t)(n0 + lrow) * K + k0 + kq];
    Bs[kq + 0][lrow] = bv.x; Bs[kq + 1][lrow] = bv.y;
    Bs[kq + 2][lrow] = bv.z; Bs[kq + 3][lrow] = bv.w;
    __syncthreads();
#pragma unroll
    for (int kk = 0; kk < 16; kk++) {
      float4 a = *(const float4*)&As[kk][ty * 4];
      float4 b = *(const float4*)&Bs[kk][tx * 4];
      float aa[4] = {a.x, a.y, a.z, a.w};
      float bb[4] = {b.x, b.y, b.z, b.w};
#pragma unroll
      for (int i = 0; i < 4; i++)
#pragma unroll
        for (int j = 0; j < 4; j++) acc[i][j] = fmaf(aa[i], bb[j], acc[i][j]);
    }
    __syncthreads();
  }
#pragma unroll
  for (int i = 0; i < 4; i++) {
    int gr = row0 + ty * 4 + i;
    if (gr >= M) continue;
#pragma unroll
    for (int j = 0; j < 4; j++) {
      int gc = n0 + tx * 4 + j;
      if (gc >= Nn) continue;
      C[(size_t)gr * Nn + gc] = acc[i][j] + bias[gc];
    }
  }
}

// ============================================================================
extern "C" void kernel_launch(void* const* d_in, const int* in_sizes, int n_in,
                              void* d_out, int out_size, void* d_ws, size_t ws_size,
                              hipStream_t stream) {
  const float* x       = (const float*)d_in[0];
  const float* patch_w = (const float*)d_in[1];
  const float* patch_b = (const float*)d_in[2];
  const float* cls_tok = (const float*)d_in[3];
  const float* ln1_w   = (const float*)d_in[4];
  const float* ln1_b   = (const float*)d_in[5];
  const float* qkv_w   = (const float*)d_in[6];
  const float* q_bias  = (const float*)d_in[7];
  const float* v_bias  = (const float*)d_in[8];
  const float* rel_tab = (const float*)d_in[9];
  const float* proj_w  = (const float*)d_in[10];
  const float* proj_b  = (const float*)d_in[11];
  const float* ln2_w   = (const float*)d_in[12];
  const float* ln2_b   = (const float*)d_in[13];
  const float* fc1_w   = (const float*)d_in[14];
  const float* fc1_b   = (const float*)d_in[15];
  const float* fc2_w   = (const float*)d_in[16];
  const float* fc2_b   = (const float*)d_in[17];
  const float* fcn_w   = (const float*)d_in[18];
  const float* fcn_b   = (const float*)d_in[19];
  const float* head_w  = (const float*)d_in[20];
  const float* head_b  = (const float*)d_in[21];
  float* outp = (float*)d_out;

  char* wsb = (char*)d_ws;
  float* h    = (float*)wsb;  wsb += 19365888;   // [6304][768] f32
  bf16* bigb  = (bf16*)wsb;   wsb += 29048832;   // [6304][2304]
  bf16* yb    = (bf16*)wsb;   wsb += 9830400;    // [6400][768]
  bf16* hid   = (bf16*)wsb;   wsb += 39321600;   // [6400][3072]
  bf16* wl    = (bf16*)wsb;   wsb += 14155776;
  bf16* vt_g  = (bf16*)wsb;   wsb += 11010048;   // [32][12][64][224]
  float* biasT = (float*)wsb; wsb += 2752512;    // [12][224][256] f32
  float* feat = (float*)wsb;

  const int M = 6304;

  vtz_k<<<2688, 256, 0, stream>>>(vt_g);
  patchify_k<<<(6272 * 768 + 255) / 256, 256, 0, stream>>>(x, hid);
  cvt_k<<<(589824 / 8 + 255) / 256, 256, 0, stream>>>(patch_w, wl, 589824 / 8);
  mm128_k<0><<<dim3(49, 6), 256, 0, stream>>>(
      hid, wl, patch_b, nullptr, h, 6272, 768, 768);
  clsfill_k<<<(32 * 768 + 255) / 256, 256, 0, stream>>>(cls_tok, h);

  for (int d = 0; d < 12; d++) {
    prep_k<<<6144, 256, 0, stream>>>(qkv_w, proj_w, fc1_w, fc2_w, rel_tab,
                                     wl, biasT, d);
    ln_k<<<dim3((M + 3) / 4), dim3(64, 4), 0, stream>>>(h, yb, ln1_w + d * 768, ln1_b + d * 768, M);
    mm256_k<1><<<dim3(25, 18), 512, 0, stream>>>(
        yb, wl, q_bias + d * 768, v_bias + d * 768, bigb, vt_g, M, 2304, 768);
    attn2_k<<<32 * NHEAD, 256, 0, stream>>>(bigb, vt_g, biasT, yb);
    mm128_k<2><<<dim3(50, 6), 256, 0, stream>>>(
        yb, wl + O_PROJ, proj_b + d * 768, h, h, M, 768, 768);
    ln_k<<<dim3((M + 3) / 4), dim3(64, 4), 0, stream>>>(h, yb, ln2_w + d * 768, ln2_b + d * 768, M);
    mm256_k<3><<<dim3(25, 24), 512, 0, stream>>>(
        yb, wl + O_FC1, fc1_b + d * 3072, nullptr, hid, nullptr, M, 3072, 768);
    mm128_k<2><<<dim3(50, 6), 256, 0, stream>>>(
        hid, wl + O_FC2, fc2_b + d * 768, h, h, M, 768, 3072);
  }

  pool_ln_k<<<32, 256, 0, stream>>>(h, fcn_w, fcn_b, feat);
  {
    dim3 g(1, (1000 + 63) / 64);
    head_k<<<g, 256, 0, stream>>>(feat, head_w, head_b, outp, 32, 1000, 768);
  }
}

// Round 14
// 3299.644 us; speedup vs baseline: 1.0333x; 1.0004x over previous
//
#include <hip/hip_runtime.h>
#include <hip/hip_bf16.h>
#include <math.h>

// ============================================================================
// BEiT ViT-B/16 forward — round 14: round-9 champion (3,296 us measured,
// reproduced r13 at 3,301) + fused prologue (vtz/patchify/cvt/clsfill in one
// launch). r6 3-ring counted-vmcnt MFMA GEMMs, fc2 de-split, fused per-layer
// prep, vectorized LN, MFMA flash attention.
// ============================================================================

typedef __hip_bfloat16 bf16;
using short8 = __attribute__((ext_vector_type(8))) short;
using f32x4  = __attribute__((ext_vector_type(4))) float;

#define NTOK 197
#define NHEAD 12
#define NPAD 224

#define S_QKV  1769472
#define S_PROJ 589824
#define S_FC   2359296
#define O_PROJ 1769472
#define O_FC1  2359296
#define O_FC2  4718592
#define W_TOT  7077888

#define GLD(gp, lp) __builtin_amdgcn_global_load_lds( \
    (const unsigned int __attribute__((address_space(1)))*)(gp), \
    (unsigned int __attribute__((address_space(3)))*)(lp), 16, 0, 0)

// ---------------- BEiT relative-position index -------------------------------
__device__ __forceinline__ int ridx(int n, int m) {
  if (n == 0) return (m == 0) ? 731 : 729;
  if (m == 0) return 730;
  int nh = (n - 1) / 14, nw = (n - 1) % 14;
  int mh = (m - 1) / 14, mw = (m - 1) % 14;
  return (nh - mh + 13) * 27 + (nw - mw + 13);
}

// ---------------- fused prologue: vtz | patchify | patch_w cvt | clsfill -----
// blocks [0,2688): zero vt; [2688,21504): patchify; [21504,21792): cvt patch_w
// (73728 short8); [21792,21888): clsfill.
__global__ __launch_bounds__(256) void pre_k(const float* __restrict__ x,
                                             const float* __restrict__ patch_w,
                                             const float* __restrict__ cls,
                                             bf16* __restrict__ vt,
                                             bf16* __restrict__ patches,
                                             bf16* __restrict__ wl,
                                             float* __restrict__ h) {
  int blk = blockIdx.x;
  if (blk < 2688) {
    int i = blk * 256 + threadIdx.x;
    *(short8*)(vt + (size_t)i * 8) = (short8){0,0,0,0,0,0,0,0};
  } else if (blk < 21504) {
    int o = (blk - 2688) * 256 + threadIdx.x;
    if (o >= 6272 * 768) return;
    int row = o / 768, col = o % 768;
    int b = row / 196, g = row % 196;
    int gh = g / 14, gw = g % 14;
    int c = col / 256, r = col % 256;
    int ph = r / 16, pw = r % 16;
    patches[o] = __float2bfloat16(
        x[(((size_t)b * 3 + c) * 224 + gh * 16 + ph) * 224 + gw * 16 + pw]);
  } else if (blk < 21792) {
    int t = (blk - 21504) * 256 + threadIdx.x;
    if (t >= 73728) return;
    size_t i = (size_t)t * 8;
    float4 a = *(const float4*)(patch_w + i);
    float4 b = *(const float4*)(patch_w + i + 4);
    union { short8 v; bf16 e[8]; } u;
    u.e[0] = __float2bfloat16(a.x); u.e[1] = __float2bfloat16(a.y);
    u.e[2] = __float2bfloat16(a.z); u.e[3] = __float2bfloat16(a.w);
    u.e[4] = __float2bfloat16(b.x); u.e[5] = __float2bfloat16(b.y);
    u.e[6] = __float2bfloat16(b.z); u.e[7] = __float2bfloat16(b.w);
    *(short8*)(wl + i) = u.v;
  } else {
    int i = (blk - 21792) * 256 + threadIdx.x;
    if (i >= 32 * 768) return;
    int b = i / 768, e = i % 768;
    h[((size_t)b * 197) * 768 + e] = cls[e];
  }
}

// ---------------- fused per-layer prep: weight cvt + bias table --------------
__global__ __launch_bounds__(256) void prep_k(
    const float* __restrict__ qkvw, const float* __restrict__ projw,
    const float* __restrict__ fc1w, const float* __restrict__ fc2w,
    const float* __restrict__ rel, bf16* __restrict__ wl,
    float* __restrict__ biasT, int d) {
  int blk = blockIdx.x;
  if (blk < 3456) {
    size_t i = ((size_t)blk * 256 + threadIdx.x) * 8;
    const float* src;
    if (i < O_PROJ)      src = qkvw + (size_t)d * S_QKV + i;
    else if (i < O_FC1)  src = projw + (size_t)d * S_PROJ + (i - O_PROJ);
    else if (i < O_FC2)  src = fc1w + (size_t)d * S_FC + (i - O_FC1);
    else                 src = fc2w + (size_t)d * S_FC + (i - O_FC2);
    float4 a = *(const float4*)src;
    float4 b = *(const float4*)(src + 4);
    union { short8 v; bf16 e[8]; } u;
    u.e[0] = __float2bfloat16(a.x); u.e[1] = __float2bfloat16(a.y);
    u.e[2] = __float2bfloat16(a.z); u.e[3] = __float2bfloat16(a.w);
    u.e[4] = __float2bfloat16(b.x); u.e[5] = __float2bfloat16(b.y);
    u.e[6] = __float2bfloat16(b.z); u.e[7] = __float2bfloat16(b.w);
    *(short8*)(wl + i) = u.v;
  } else {
    int idx = (blk - 3456) * 256 + threadIdx.x;
    int h = idx / (NPAD * 256);
    int rem = idx % (NPAD * 256);
    int m = rem / 256, n = rem % 256;
    float v;
    if (m >= NTOK) {
      v = -1e30f;
    } else {
      int nn = min(n, NTOK - 1);
      v = rel[((size_t)d * 732 + ridx(nn, m)) * 12 + h];
    }
    biasT[idx] = v;
  }
}

// ============================================================================
// mm256: 3-ring counted-vmcnt MFMA GEMM, BM=256 x BN=128, BK=32, 512 thr /
// 8 waves (4m x 2n), per-wave 64x64. LDS = 3 x 24KB = 72KB -> 2 blocks/CU.
// r6-proven schedule: prologue vmcnt(3), loop vmcnt(2).
// EPI: 1=qkv (split bias, Q/K->bf16, V->vt), 3=fc1 (bias+gelu->bf16).
// ============================================================================
template <int EPI>
__global__ __launch_bounds__(512, 4) void mm256_k(
    const bf16* __restrict__ A, const bf16* __restrict__ W,
    const float* __restrict__ bias, const float* __restrict__ bias2,
    void* __restrict__ Cout, bf16* __restrict__ vtg,
    int M, int Nn, int K) {
  constexpr int BUFSZ = 24576;
  __shared__ __attribute__((aligned(16))) char lds[3 * BUFSZ];
  const int tid = threadIdx.x;
  const int lane = tid & 63, wave = tid >> 6;
  const int wr = wave >> 1, wc = wave & 1;
  const int l15 = lane & 15, lg = lane >> 4;
  const int row0 = blockIdx.x * 256, n0 = blockIdx.y * 128;
  const int nt = K >> 5, ntm1 = nt - 1;

  const bf16 *gA0, *gA1, *gB0;
  int dA0, dA1, dB0;
  {
    int s = tid * 16;
    int r = s >> 6, cl = ((s >> 4) & 3) ^ ((r >> 1) & 3);
    gA0 = A + (size_t)(row0 + r) * K + cl * 8;  dA0 = s;
    s = 8192 + tid * 16;
    r = s >> 6; cl = ((s >> 4) & 3) ^ ((r >> 1) & 3);
    gA1 = A + (size_t)(row0 + r) * K + cl * 8;  dA1 = s;
    s = tid * 16;
    r = s >> 6; cl = ((s >> 4) & 3) ^ ((r >> 1) & 3);
    gB0 = W + (size_t)(n0 + r) * K + cl * 8;    dB0 = 16384 + s;
  }
  int oA[4], oB[4];
#pragma unroll
  for (int m = 0; m < 4; m++) {
    int r = wr * 64 + m * 16 + l15;
    oA[m] = (r << 6) | ((lg ^ ((r >> 1) & 3)) << 4);
  }
#pragma unroll
  for (int n = 0; n < 4; n++) {
    int r = wc * 64 + n * 16 + l15;
    oB[n] = 16384 + ((r << 6) | ((lg ^ ((r >> 1) & 3)) << 4));
  }

  f32x4 acc[4][4];
#pragma unroll
  for (int m = 0; m < 4; m++)
#pragma unroll
    for (int n = 0; n < 4; n++) acc[m][n] = (f32x4){0.f, 0.f, 0.f, 0.f};

  GLD(gA0, lds + dA0); GLD(gA1, lds + dA1); GLD(gB0, lds + dB0);
  GLD(gA0 + 32, lds + BUFSZ + dA0); GLD(gA1 + 32, lds + BUFSZ + dA1);
  GLD(gB0 + 32, lds + BUFSZ + dB0);
  asm volatile("s_waitcnt vmcnt(3)" ::: "memory");
  __builtin_amdgcn_s_barrier();
  __builtin_amdgcn_sched_barrier(0);

#define MB(RB, WB, tt)                                                        \
  {                                                                           \
    int ks = (tt) + 2; if (ks > ntm1) ks = ntm1; ks <<= 5;                    \
    char* wb = lds + (WB) * BUFSZ;                                            \
    GLD(gA0 + ks, wb + dA0); GLD(gA1 + ks, wb + dA1);                         \
    GLD(gB0 + ks, wb + dB0);                                                  \
    const char* rb = lds + (RB) * BUFSZ;                                      \
    short8 a[4], b[4];                                                        \
    _Pragma("unroll") for (int m = 0; m < 4; m++)                             \
      a[m] = *(const short8*)(rb + oA[m]);                                    \
    _Pragma("unroll") for (int n = 0; n < 4; n++)                             \
      b[n] = *(const short8*)(rb + oB[n]);                                    \
    __builtin_amdgcn_s_setprio(1);                                            \
    _Pragma("unroll") for (int m = 0; m < 4; m++)                             \
      _Pragma("unroll") for (int n = 0; n < 4; n++)                           \
        acc[m][n] = __builtin_amdgcn_mfma_f32_16x16x32_bf16(a[m], b[n], acc[m][n], 0, 0, 0); \
    __builtin_amdgcn_s_setprio(0);                                            \
    __builtin_amdgcn_sched_barrier(0);                                        \
    asm volatile("s_waitcnt vmcnt(2)" ::: "memory");                          \
    __builtin_amdgcn_s_barrier();                                             \
    __builtin_amdgcn_sched_barrier(0);                                        \
  }

  for (int t = 0; t < nt; t += 3) {  // nt % 3 == 0
    MB(0, 2, t); MB(1, 0, t + 1); MB(2, 1, t + 2);
  }
#undef MB
  asm volatile("s_waitcnt vmcnt(0)" ::: "memory");

#pragma unroll
  for (int m = 0; m < 4; m++) {
    const int rbase = row0 + wr * 64 + m * 16 + lg * 4;
#pragma unroll
    for (int n = 0; n < 4; n++) {
      const int gc = n0 + wc * 64 + n * 16 + l15;
      f32x4 v = acc[m][n];
#pragma unroll
      for (int j = 0; j < 4; j++) {
        int gr = rbase + j;
        if (gr >= M) continue;
        float val = v[j];
        if (EPI == 1) {
          if (gc < 768) val += bias[gc];
          else if (gc >= 1536) val += bias2[gc - 1536];
          if (gc >= 1536) {
            int ob = gr / 197, nn = gr - ob * 197, hd = gc - 1536;
            vtg[(((size_t)ob * 12 + (hd >> 6)) * 64 + (hd & 63)) * NPAD + nn] =
                __float2bfloat16(val);
          } else {
            ((bf16*)Cout)[(size_t)gr * Nn + gc] = __float2bfloat16(val);
          }
        } else {  // EPI == 3
          val += bias[gc];
          val = 0.5f * val * (1.f + erff(val * 0.70710678118654752f));
          ((bf16*)Cout)[(size_t)gr * Nn + gc] = __float2bfloat16(val);
        }
      }
    }
  }
}

// ============================================================================
// mm128: 3-ring counted-vmcnt, BM=BN=128, BK=32, 256 thr / 4 waves (2x2),
// per-wave 64x64. LDS = 48KB -> 3 blocks/CU. r6 schedule: prologue vmcnt(4),
// loop vmcnt(3). EPI: 0=patch (bias, f32, remap), 2=bias+residual (f32).
// ============================================================================
template <int EPI>
__global__ __launch_bounds__(256, 3) void mm128_k(
    const bf16* __restrict__ A, const bf16* __restrict__ W,
    const float* __restrict__ bias, const float* __restrict__ Res,
    void* __restrict__ Cout, int M, int Nn, int K) {
  constexpr int BUFSZ = 16384;
  __shared__ __attribute__((aligned(16))) char lds[3 * BUFSZ];
  const int tid = threadIdx.x;
  const int lane = tid & 63, wave = tid >> 6;
  const int wr = wave >> 1, wc = wave & 1;
  const int l15 = lane & 15, lg = lane >> 4;
  const int row0 = blockIdx.x * 128, n0 = blockIdx.y * 128;
  const int nt = K >> 5, ntm1 = nt - 1;

  const bf16 *gA0, *gA1, *gB0, *gB1;
  int dA0, dA1, dB0, dB1;
  {
    int s = tid * 16;
    int r = s >> 6, cl = ((s >> 4) & 3) ^ ((r >> 1) & 3);
    gA0 = A + (size_t)(row0 + r) * K + cl * 8;  dA0 = s;
    s = 4096 + tid * 16;
    r = s >> 6; cl = ((s >> 4) & 3) ^ ((r >> 1) & 3);
    gA1 = A + (size_t)(row0 + r) * K + cl * 8;  dA1 = s;
    s = tid * 16;
    r = s >> 6; cl = ((s >> 4) & 3) ^ ((r >> 1) & 3);
    gB0 = W + (size_t)(n0 + r) * K + cl * 8;    dB0 = 8192 + s;
    s = 4096 + tid * 16;
    r = s >> 6; cl = ((s >> 4) & 3) ^ ((r >> 1) & 3);
    gB1 = W + (size_t)(n0 + r) * K + cl * 8;    dB1 = 8192 + s;
  }
  int oA[4], oB[4];
#pragma unroll
  for (int m = 0; m < 4; m++) {
    int r = wr * 64 + m * 16 + l15;
    oA[m] = (r << 6) | ((lg ^ ((r >> 1) & 3)) << 4);
  }
#pragma unroll
  for (int n = 0; n < 4; n++) {
    int r = wc * 64 + n * 16 + l15;
    oB[n] = 8192 + ((r << 6) | ((lg ^ ((r >> 1) & 3)) << 4));
  }

  f32x4 acc[4][4];
#pragma unroll
  for (int m = 0; m < 4; m++)
#pragma unroll
    for (int n = 0; n < 4; n++) acc[m][n] = (f32x4){0.f, 0.f, 0.f, 0.f};

  GLD(gA0, lds + dA0); GLD(gA1, lds + dA1);
  GLD(gB0, lds + dB0); GLD(gB1, lds + dB1);
  GLD(gA0 + 32, lds + BUFSZ + dA0); GLD(gA1 + 32, lds + BUFSZ + dA1);
  GLD(gB0 + 32, lds + BUFSZ + dB0); GLD(gB1 + 32, lds + BUFSZ + dB1);
  asm volatile("s_waitcnt vmcnt(4)" ::: "memory");
  __builtin_amdgcn_s_barrier();
  __builtin_amdgcn_sched_barrier(0);

#define MB(RB, WB, tt)                                                        \
  {                                                                           \
    int ks = (tt) + 2; if (ks > ntm1) ks = ntm1; ks <<= 5;                    \
    char* wb = lds + (WB) * BUFSZ;                                            \
    GLD(gA0 + ks, wb + dA0); GLD(gA1 + ks, wb + dA1);                         \
    GLD(gB0 + ks, wb + dB0); GLD(gB1 + ks, wb + dB1);                         \
    const char* rb = lds + (RB) * BUFSZ;                                      \
    short8 a[4], b[4];                                                        \
    _Pragma("unroll") for (int m = 0; m < 4; m++)                             \
      a[m] = *(const short8*)(rb + oA[m]);                                    \
    _Pragma("unroll") for (int n = 0; n < 4; n++)                             \
      b[n] = *(const short8*)(rb + oB[n]);                                    \
    __builtin_amdgcn_s_setprio(1);                                            \
    _Pragma("unroll") for (int m = 0; m < 4; m++)                             \
      _Pragma("unroll") for (int n = 0; n < 4; n++)                           \
        acc[m][n] = __builtin_amdgcn_mfma_f32_16x16x32_bf16(a[m], b[n], acc[m][n], 0, 0, 0); \
    __builtin_amdgcn_s_setprio(0);                                            \
    __builtin_amdgcn_sched_barrier(0);                                        \
    asm volatile("s_waitcnt vmcnt(3)" ::: "memory");                          \
    __builtin_amdgcn_s_barrier();                                             \
    __builtin_amdgcn_sched_barrier(0);                                        \
  }

  for (int t = 0; t < nt; t += 3) {  // nt % 3 == 0
    MB(0, 2, t); MB(1, 0, t + 1); MB(2, 1, t + 2);
  }
#undef MB
  asm volatile("s_waitcnt vmcnt(0)" ::: "memory");

#pragma unroll
  for (int m = 0; m < 4; m++) {
    const int rbase = row0 + wr * 64 + m * 16 + lg * 4;
#pragma unroll
    for (int n = 0; n < 4; n++) {
      const int gc = n0 + wc * 64 + n * 16 + l15;
      f32x4 v = acc[m][n];
#pragma unroll
      for (int j = 0; j < 4; j++) {
        int gr = rbase + j;
        if (gr >= M) continue;
        float val = v[j] + bias[gc];
        if (EPI == 2) val += Res[(size_t)gr * Nn + gc];
        int orow = (EPI == 0) ? (gr + gr / 196 + 1) : gr;
        ((float*)Cout)[(size_t)orow * Nn + gc] = val;
      }
    }
  }
}

// ---------------- LayerNorm (768), fp32 in -> bf16 out, vectorized ----------
__global__ __launch_bounds__(256) void ln_k(const float* __restrict__ in,
                                            bf16* __restrict__ outp,
                                            const float* __restrict__ w,
                                            const float* __restrict__ b,
                                            int rows) {
  int row = blockIdx.x * 4 + threadIdx.y;
  if (row >= rows) return;
  int lane = threadIdx.x;
  const float4* xr = (const float4*)(in + (size_t)row * 768);
  float4 v[3];
  float s = 0.f;
#pragma unroll
  for (int i = 0; i < 3; i++) {
    v[i] = xr[lane + i * 64];
    s += (v[i].x + v[i].y) + (v[i].z + v[i].w);
  }
#pragma unroll
  for (int o = 32; o; o >>= 1) s += __shfl_xor(s, o);
  float mean = s * (1.f / 768.f);
  float var = 0.f;
#pragma unroll
  for (int i = 0; i < 3; i++) {
    float d0 = v[i].x - mean, d1 = v[i].y - mean;
    float d2 = v[i].z - mean, d3 = v[i].w - mean;
    var += (d0 * d0 + d1 * d1) + (d2 * d2 + d3 * d3);
  }
#pragma unroll
  for (int o = 32; o; o >>= 1) var += __shfl_xor(var, o);
  float rs = rsqrtf(var * (1.f / 768.f) + 1e-5f);
  const float4* w4 = (const float4*)w;
  const float4* b4 = (const float4*)b;
  bf16* orow = outp + (size_t)row * 768;
#pragma unroll
  for (int i = 0; i < 3; i++) {
    int e4 = lane + i * 64;
    float4 wv = w4[e4], bv = b4[e4];
    union { bf16 h; short s; } c0, c1, c2, c3;
    c0.h = __float2bfloat16((v[i].x - mean) * rs * wv.x + bv.x);
    c1.h = __float2bfloat16((v[i].y - mean) * rs * wv.y + bv.y);
    c2.h = __float2bfloat16((v[i].z - mean) * rs * wv.z + bv.z);
    c3.h = __float2bfloat16((v[i].w - mean) * rs * wv.w + bv.w);
    short4 o4 = make_short4(c0.s, c1.s, c2.s, c3.s);
    *(short4*)(orow + e4 * 4) = o4;
  }
}

// ---------------- MFMA flash attention --------------------------------------
__device__ __forceinline__ unsigned pkbf(float a, float b) {
  union { bf16 h; unsigned short u; } ua, ub;
  ua.h = __float2bfloat16(a); ub.h = __float2bfloat16(b);
  return ((unsigned)ub.u << 16) | (unsigned)ua.u;
}

__global__ __launch_bounds__(256) void attn2_k(const bf16* __restrict__ qkvb,
                                               const bf16* __restrict__ vtg,
                                               const float* __restrict__ biasT,
                                               bf16* __restrict__ outp) {
  __shared__ bf16 Ks[NPAD * 64];
  __shared__ bf16 Vt[64 * NPAD];
  __shared__ bf16 Ps[4][64 * 32];
  __shared__ float denl[4][64];

  const int bh = blockIdx.x;
  const int b = bh / 12, h = bh % 12;
  const int tid = threadIdx.x;
  const int wave = tid >> 6, lane = tid & 63;
  const int l15 = lane & 15, lg = lane >> 4;
  const int qbase = wave * 64;

  const bf16* vsrc = vtg + (size_t)bh * 64 * NPAD;
#pragma unroll
  for (int i = 0; i < 7; i++) {
    int c = i * 256 + tid;
    GLD(vsrc + c * 8, Vt + c * 8);
  }
#pragma unroll
  for (int i = 0; i < 7; i++) {
    int slot = i * 256 + tid;
    int r = slot >> 3, c8 = (slot & 7) * 8;
    int rg = min(r, NTOK - 1);
    short8 kv = *(const short8*)(qkvb + (size_t)(b * NTOK + rg) * 2304 + 768 + h * 64 + c8);
    int byte = (r * 128 + c8 * 2) ^ ((r & 7) << 4);
    *(short8*)((char*)Ks + byte) = kv;
  }
  short8 qf[4][2];
#pragma unroll
  for (int nf = 0; nf < 4; nf++) {
    int n = qbase + nf * 16 + l15;
    const bf16* qp = qkvb + (size_t)(b * NTOK + min(n, NTOK - 1)) * 2304 + h * 64;
    qf[nf][0] = *(const short8*)(qp + lg * 8);
    qf[nf][1] = *(const short8*)(qp + 32 + lg * 8);
  }
  __syncthreads();

  f32x4 Oacc[4][4];
#pragma unroll
  for (int i = 0; i < 4; i++)
#pragma unroll
    for (int j = 0; j < 4; j++) Oacc[i][j] = (f32x4){0.f, 0.f, 0.f, 0.f};
  float den[4] = {0.f, 0.f, 0.f, 0.f};
  const float* bT = biasT + (size_t)h * NPAD * 256;
  char* pw = (char*)&Ps[wave][0];

  for (int c = 0; c < 7; c++) {
    const int m0 = c * 32;
    f32x4 st[2][4];
#pragma unroll
    for (int mf = 0; mf < 2; mf++)
#pragma unroll
      for (int nf = 0; nf < 4; nf++) st[mf][nf] = (f32x4){0.f, 0.f, 0.f, 0.f};
#pragma unroll
    for (int kk = 0; kk < 2; kk++) {
      short8 af[2];
#pragma unroll
      for (int mf = 0; mf < 2; mf++) {
        int m = m0 + mf * 16 + l15;
        int byte = (m * 128 + kk * 64 + lg * 16) ^ ((m & 7) << 4);
        af[mf] = *(const short8*)((const char*)Ks + byte);
      }
#pragma unroll
      for (int mf = 0; mf < 2; mf++)
#pragma unroll
        for (int nf = 0; nf < 4; nf++)
          st[mf][nf] = __builtin_amdgcn_mfma_f32_16x16x32_bf16(af[mf], qf[nf][kk], st[mf][nf], 0, 0, 0);
    }
#pragma unroll
    for (int mf = 0; mf < 2; mf++) {
      int mrow = m0 + mf * 16 + lg * 4;
#pragma unroll
      for (int nf = 0; nf < 4; nf++) {
        int n = qbase + nf * 16 + l15;
        float p0 = __expf(st[mf][nf][0] * 0.125f + bT[(mrow + 0) * 256 + n]);
        float p1 = __expf(st[mf][nf][1] * 0.125f + bT[(mrow + 1) * 256 + n]);
        float p2 = __expf(st[mf][nf][2] * 0.125f + bT[(mrow + 2) * 256 + n]);
        float p3 = __expf(st[mf][nf][3] * 0.125f + bT[(mrow + 3) * 256 + n]);
        den[nf] += (p0 + p1) + (p2 + p3);
        int nl = nf * 16 + l15;
        int byte = (nl * 64 + (mf * 16 + lg * 4) * 2) ^ ((nl & 7) << 4);
        *(unsigned*)(pw + byte) = pkbf(p0, p1);
        *(unsigned*)(pw + byte + 4) = pkbf(p2, p3);
      }
    }
    short8 pa[4], vb[4];
#pragma unroll
    for (int nf = 0; nf < 4; nf++) {
      int nl = nf * 16 + l15;
      int byte = (nl * 64 + lg * 16) ^ ((nl & 7) << 4);
      pa[nf] = *(const short8*)((const char*)pw + byte);
    }
#pragma unroll
    for (int df = 0; df < 4; df++) {
      int d = df * 16 + l15;
      vb[df] = *(const short8*)(Vt + d * NPAD + m0 + lg * 8);
    }
#pragma unroll
    for (int nf = 0; nf < 4; nf++)
#pragma unroll
      for (int df = 0; df < 4; df++)
        Oacc[nf][df] = __builtin_amdgcn_mfma_f32_16x16x32_bf16(pa[nf], vb[df], Oacc[nf][df], 0, 0, 0);
  }

#pragma unroll
  for (int nf = 0; nf < 4; nf++) {
    den[nf] += __shfl_xor(den[nf], 16);
    den[nf] += __shfl_xor(den[nf], 32);
    denl[wave][nf * 16 + l15] = den[nf];
  }
  float inv[4][4];
#pragma unroll
  for (int nf = 0; nf < 4; nf++)
#pragma unroll
    for (int j = 0; j < 4; j++)
      inv[nf][j] = 1.f / denl[wave][nf * 16 + lg * 4 + j];
#pragma unroll
  for (int nf = 0; nf < 4; nf++) {
#pragma unroll
    for (int df = 0; df < 4; df++) {
#pragma unroll
      for (int j = 0; j < 4; j++) {
        int n = qbase + nf * 16 + lg * 4 + j;
        if (n < NTOK)
          outp[(size_t)(b * NTOK + n) * 768 + h * 64 + df * 16 + l15] =
              __float2bfloat16(Oacc[nf][df][j] * inv[nf][j]);
      }
    }
  }
}

// ---------------- mean-pool + LayerNorm -------------------------------------
__device__ __forceinline__ float block_sum(float v, float* sm4) {
#pragma unroll
  for (int o = 32; o; o >>= 1) v += __shfl_down(v, o);
  __syncthreads();
  if ((threadIdx.x & 63) == 0) sm4[threadIdx.x >> 6] = v;
  __syncthreads();
  return sm4[0] + sm4[1] + sm4[2] + sm4[3];
}

__global__ __launch_bounds__(256) void pool_ln_k(const float* __restrict__ h,
                                                 const float* __restrict__ w,
                                                 const float* __restrict__ bi,
                                                 float* __restrict__ feat) {
  __shared__ float sm4[4];
  int b = blockIdx.x, tid = threadIdx.x;
  float vals[3];
  float local = 0.f;
#pragma unroll
  for (int j = 0; j < 3; j++) {
    int e = tid + j * 256;
    float s = 0.f;
    for (int nn = 1; nn < 197; nn++) s += h[((size_t)(b * 197 + nn)) * 768 + e];
    s *= (1.f / 196.f);
    vals[j] = s;
    local += s;
  }
  float tot = block_sum(local, sm4);
  float mean = tot * (1.f / 768.f);
  float lv = 0.f;
#pragma unroll
  for (int j = 0; j < 3; j++) { float d = vals[j] - mean; lv += d * d; }
  float vtot = block_sum(lv, sm4);
  float rs = rsqrtf(vtot * (1.f / 768.f) + 1e-5f);
#pragma unroll
  for (int j = 0; j < 3; j++) {
    int e = tid + j * 256;
    feat[(size_t)b * 768 + e] = (vals[j] - mean) * rs * w[e] + bi[e];
  }
}

// ---------------- small fp32 GEMM for the head ------------------------------
__global__ __launch_bounds__(256) void head_k(const float* __restrict__ A,
                                              const float* __restrict__ W,
                                              const float* __restrict__ bias,
                                              float* __restrict__ C,
                                              int M, int Nn, int K) {
  __shared__ float As[16][64 + 4];
  __shared__ float Bs[16][64 + 4];
  int tid = threadIdx.x;
  int tx = tid & 15, ty = tid >> 4;
  int row0 = blockIdx.x * 64, n0 = blockIdx.y * 64;
  int lrow = tid >> 2;
  int kq = (tid & 3) * 4;
  float acc[4][4];
#pragma unroll
  for (int i = 0; i < 4; i++)
#pragma unroll
    for (int j = 0; j < 4; j++) acc[i][j] = 0.f;
  for (int k0 = 0; k0 < K; k0 += 16) {
    float4 av = make_float4(0.f, 0.f, 0.f, 0.f);
    if (row0 + lrow < M) av = *(const float4*)&A[(size_t)(row0 + lrow) * K + k0 + kq];
    As[kq + 0][lrow] = av.x; As[kq + 1][lrow] = av.y;
    As[kq + 2][lrow] = av.z; As[kq + 3][lrow] = av.w;
    float4 bv = make_float4(0.f, 0.f, 0.f, 0.f);
    if (n0 + lrow < Nn) bv = *(const float4*)&W[(size_t)(n0 + lrow) * K + k0 + kq];
    Bs[kq + 0][lrow] = bv.x; Bs[kq + 1][lrow] = bv.y;
    Bs[kq + 2][lrow] = bv.z; Bs[kq + 3][lrow] = bv.w;
    __syncthreads();
#pragma unroll
    for (int kk = 0; kk < 16; kk++) {
      float4 a = *(const float4*)&As[kk][ty * 4];
      float4 b = *(const float4*)&Bs[kk][tx * 4];
      float aa[4] = {a.x, a.y, a.z, a.w};
      float bb[4] = {b.x, b.y, b.z, b.w};
#pragma unroll
      for (int i = 0; i < 4; i++)
#pragma unroll
        for (int j = 0; j < 4; j++) acc[i][j] = fmaf(aa[i], bb[j], acc[i][j]);
    }
    __syncthreads();
  }
#pragma unroll
  for (int i = 0; i < 4; i++) {
    int gr = row0 + ty * 4 + i;
    if (gr >= M) continue;
#pragma unroll
    for (int j = 0; j < 4; j++) {
      int gc = n0 + tx * 4 + j;
      if (gc >= Nn) continue;
      C[(size_t)gr * Nn + gc] = acc[i][j] + bias[gc];
    }
  }
}

// ============================================================================
extern "C" void kernel_launch(void* const* d_in, const int* in_sizes, int n_in,
                              void* d_out, int out_size, void* d_ws, size_t ws_size,
                              hipStream_t stream) {
  const float* x       = (const float*)d_in[0];
  const float* patch_w = (const float*)d_in[1];
  const float* patch_b = (const float*)d_in[2];
  const float* cls_tok = (const float*)d_in[3];
  const float* ln1_w   = (const float*)d_in[4];
  const float* ln1_b   = (const float*)d_in[5];
  const float* qkv_w   = (const float*)d_in[6];
  const float* q_bias  = (const float*)d_in[7];
  const float* v_bias  = (const float*)d_in[8];
  const float* rel_tab = (const float*)d_in[9];
  const float* proj_w  = (const float*)d_in[10];
  const float* proj_b  = (const float*)d_in[11];
  const float* ln2_w   = (const float*)d_in[12];
  const float* ln2_b   = (const float*)d_in[13];
  const float* fc1_w   = (const float*)d_in[14];
  const float* fc1_b   = (const float*)d_in[15];
  const float* fc2_w   = (const float*)d_in[16];
  const float* fc2_b   = (const float*)d_in[17];
  const float* fcn_w   = (const float*)d_in[18];
  const float* fcn_b   = (const float*)d_in[19];
  const float* head_w  = (const float*)d_in[20];
  const float* head_b  = (const float*)d_in[21];
  float* outp = (float*)d_out;

  char* wsb = (char*)d_ws;
  float* h    = (float*)wsb;  wsb += 19365888;   // [6304][768] f32
  bf16* bigb  = (bf16*)wsb;   wsb += 29048832;   // [6304][2304]
  bf16* yb    = (bf16*)wsb;   wsb += 9830400;    // [6400][768]
  bf16* hid   = (bf16*)wsb;   wsb += 39321600;   // [6400][3072]
  bf16* wl    = (bf16*)wsb;   wsb += 14155776;
  bf16* vt_g  = (bf16*)wsb;   wsb += 11010048;   // [32][12][64][224]
  float* biasT = (float*)wsb; wsb += 2752512;    // [12][224][256] f32
  float* feat = (float*)wsb;

  const int M = 6304;

  // fused prologue: vtz | patchify | patch_w cvt | clsfill
  pre_k<<<21888, 256, 0, stream>>>(x, patch_w, cls_tok, vt_g, hid, wl, h);
  mm128_k<0><<<dim3(49, 6), 256, 0, stream>>>(
      hid, wl, patch_b, nullptr, h, 6272, 768, 768);

  for (int d = 0; d < 12; d++) {
    prep_k<<<6144, 256, 0, stream>>>(qkv_w, proj_w, fc1_w, fc2_w, rel_tab,
                                     wl, biasT, d);
    ln_k<<<dim3((M + 3) / 4), dim3(64, 4), 0, stream>>>(h, yb, ln1_w + d * 768, ln1_b + d * 768, M);
    mm256_k<1><<<dim3(25, 18), 512, 0, stream>>>(
        yb, wl, q_bias + d * 768, v_bias + d * 768, bigb, vt_g, M, 2304, 768);
    attn2_k<<<32 * NHEAD, 256, 0, stream>>>(bigb, vt_g, biasT, yb);
    mm128_k<2><<<dim3(50, 6), 256, 0, stream>>>(
        yb, wl + O_PROJ, proj_b + d * 768, h, h, M, 768, 768);
    ln_k<<<dim3((M + 3) / 4), dim3(64, 4), 0, stream>>>(h, yb, ln2_w + d * 768, ln2_b + d * 768, M);
    mm256_k<3><<<dim3(25, 24), 512, 0, stream>>>(
        yb, wl + O_FC1, fc1_b + d * 3072, nullptr, hid, nullptr, M, 3072, 768);
    mm128_k<2><<<dim3(50, 6), 256, 0, stream>>>(
        hid, wl + O_FC2, fc2_b + d * 768, h, h, M, 768, 3072);
  }

  pool_ln_k<<<32, 256, 0, stream>>>(h, fcn_w, fcn_b, feat);
  {
    dim3 g(1, (1000 + 63) / 64);
    head_k<<<g, 256, 0, stream>>>(feat, head_w, head_b, outp, 32, 1000, 768);
  }
}

// Round 15
// 3295.178 us; speedup vs baseline: 1.0347x; 1.0014x over previous
//
#include <hip/hip_runtime.h>
#include <hip/hip_bf16.h>
#include <math.h>

// ============================================================================
// BEiT ViT-B/16 forward — round 15: champion (r9/r13/r14, 3,296-3,301 us) +
// per-layer prep fused with LN1 into one launch (prepln_k). r6 3-ring
// counted-vmcnt MFMA GEMMs, fc2 de-split, vectorized LN, MFMA flash attn.
// ============================================================================

typedef __hip_bfloat16 bf16;
using short8 = __attribute__((ext_vector_type(8))) short;
using f32x4  = __attribute__((ext_vector_type(4))) float;

#define NTOK 197
#define NHEAD 12
#define NPAD 224

#define S_QKV  1769472
#define S_PROJ 589824
#define S_FC   2359296
#define O_PROJ 1769472
#define O_FC1  2359296
#define O_FC2  4718592
#define W_TOT  7077888

#define GLD(gp, lp) __builtin_amdgcn_global_load_lds( \
    (const unsigned int __attribute__((address_space(1)))*)(gp), \
    (unsigned int __attribute__((address_space(3)))*)(lp), 16, 0, 0)

// ---------------- BEiT relative-position index -------------------------------
__device__ __forceinline__ int ridx(int n, int m) {
  if (n == 0) return (m == 0) ? 731 : 729;
  if (m == 0) return 730;
  int nh = (n - 1) / 14, nw = (n - 1) % 14;
  int mh = (m - 1) / 14, mw = (m - 1) % 14;
  return (nh - mh + 13) * 27 + (nw - mw + 13);
}

// ---------------- fused prologue: vtz | patchify | patch_w cvt | clsfill -----
__global__ __launch_bounds__(256) void pre_k(const float* __restrict__ x,
                                             const float* __restrict__ patch_w,
                                             const float* __restrict__ cls,
                                             bf16* __restrict__ vt,
                                             bf16* __restrict__ patches,
                                             bf16* __restrict__ wl,
                                             float* __restrict__ h) {
  int blk = blockIdx.x;
  if (blk < 2688) {
    int i = blk * 256 + threadIdx.x;
    *(short8*)(vt + (size_t)i * 8) = (short8){0,0,0,0,0,0,0,0};
  } else if (blk < 21504) {
    int o = (blk - 2688) * 256 + threadIdx.x;
    if (o >= 6272 * 768) return;
    int row = o / 768, col = o % 768;
    int b = row / 196, g = row % 196;
    int gh = g / 14, gw = g % 14;
    int c = col / 256, r = col % 256;
    int ph = r / 16, pw = r % 16;
    patches[o] = __float2bfloat16(
        x[(((size_t)b * 3 + c) * 224 + gh * 16 + ph) * 224 + gw * 16 + pw]);
  } else if (blk < 21792) {
    int t = (blk - 21504) * 256 + threadIdx.x;
    if (t >= 73728) return;
    size_t i = (size_t)t * 8;
    float4 a = *(const float4*)(patch_w + i);
    float4 b = *(const float4*)(patch_w + i + 4);
    union { short8 v; bf16 e[8]; } u;
    u.e[0] = __float2bfloat16(a.x); u.e[1] = __float2bfloat16(a.y);
    u.e[2] = __float2bfloat16(a.z); u.e[3] = __float2bfloat16(a.w);
    u.e[4] = __float2bfloat16(b.x); u.e[5] = __float2bfloat16(b.y);
    u.e[6] = __float2bfloat16(b.z); u.e[7] = __float2bfloat16(b.w);
    *(short8*)(wl + i) = u.v;
  } else {
    int i = (blk - 21792) * 256 + threadIdx.x;
    if (i >= 32 * 768) return;
    int b = i / 768, e = i % 768;
    h[((size_t)b * 197) * 768 + e] = cls[e];
  }
}

// ---------------- LN row body (flat 256-thread, 4 rows/block) ----------------
__device__ __forceinline__ void ln_body(const float* __restrict__ in,
                                        bf16* __restrict__ outp,
                                        const float* __restrict__ w,
                                        const float* __restrict__ b,
                                        int row, int rows) {
  if (row >= rows) return;
  int lane = threadIdx.x & 63;
  const float4* xr = (const float4*)(in + (size_t)row * 768);
  float4 v[3];
  float s = 0.f;
#pragma unroll
  for (int i = 0; i < 3; i++) {
    v[i] = xr[lane + i * 64];
    s += (v[i].x + v[i].y) + (v[i].z + v[i].w);
  }
#pragma unroll
  for (int o = 32; o; o >>= 1) s += __shfl_xor(s, o);
  float mean = s * (1.f / 768.f);
  float var = 0.f;
#pragma unroll
  for (int i = 0; i < 3; i++) {
    float d0 = v[i].x - mean, d1 = v[i].y - mean;
    float d2 = v[i].z - mean, d3 = v[i].w - mean;
    var += (d0 * d0 + d1 * d1) + (d2 * d2 + d3 * d3);
  }
#pragma unroll
  for (int o = 32; o; o >>= 1) var += __shfl_xor(var, o);
  float rs = rsqrtf(var * (1.f / 768.f) + 1e-5f);
  const float4* w4 = (const float4*)w;
  const float4* b4 = (const float4*)b;
  bf16* orow = outp + (size_t)row * 768;
#pragma unroll
  for (int i = 0; i < 3; i++) {
    int e4 = lane + i * 64;
    float4 wv = w4[e4], bv = b4[e4];
    union { bf16 h; short s; } c0, c1, c2, c3;
    c0.h = __float2bfloat16((v[i].x - mean) * rs * wv.x + bv.x);
    c1.h = __float2bfloat16((v[i].y - mean) * rs * wv.y + bv.y);
    c2.h = __float2bfloat16((v[i].z - mean) * rs * wv.z + bv.z);
    c3.h = __float2bfloat16((v[i].w - mean) * rs * wv.w + bv.w);
    short4 o4 = make_short4(c0.s, c1.s, c2.s, c3.s);
    *(short4*)(orow + e4 * 4) = o4;
  }
}

// ---------------- fused per-layer prep (wcvt + biasT) + LN1 ------------------
// blocks [0,3456): weight cvt; [3456,6144): biasT; [6144,7720): LN1 (4 rows ea).
__global__ __launch_bounds__(256) void prepln_k(
    const float* __restrict__ qkvw, const float* __restrict__ projw,
    const float* __restrict__ fc1w, const float* __restrict__ fc2w,
    const float* __restrict__ rel, bf16* __restrict__ wl,
    float* __restrict__ biasT,
    const float* __restrict__ hin, bf16* __restrict__ ybo,
    const float* __restrict__ lnw, const float* __restrict__ lnb, int d) {
  int blk = blockIdx.x;
  if (blk < 3456) {
    size_t i = ((size_t)blk * 256 + threadIdx.x) * 8;
    const float* src;
    if (i < O_PROJ)      src = qkvw + (size_t)d * S_QKV + i;
    else if (i < O_FC1)  src = projw + (size_t)d * S_PROJ + (i - O_PROJ);
    else if (i < O_FC2)  src = fc1w + (size_t)d * S_FC + (i - O_FC1);
    else                 src = fc2w + (size_t)d * S_FC + (i - O_FC2);
    float4 a = *(const float4*)src;
    float4 b = *(const float4*)(src + 4);
    union { short8 v; bf16 e[8]; } u;
    u.e[0] = __float2bfloat16(a.x); u.e[1] = __float2bfloat16(a.y);
    u.e[2] = __float2bfloat16(a.z); u.e[3] = __float2bfloat16(a.w);
    u.e[4] = __float2bfloat16(b.x); u.e[5] = __float2bfloat16(b.y);
    u.e[6] = __float2bfloat16(b.z); u.e[7] = __float2bfloat16(b.w);
    *(short8*)(wl + i) = u.v;
  } else if (blk < 6144) {
    int idx = (blk - 3456) * 256 + threadIdx.x;
    int h = idx / (NPAD * 256);
    int rem = idx % (NPAD * 256);
    int m = rem / 256, n = rem % 256;
    float v;
    if (m >= NTOK) {
      v = -1e30f;
    } else {
      int nn = min(n, NTOK - 1);
      v = rel[((size_t)d * 732 + ridx(nn, m)) * 12 + h];
    }
    biasT[idx] = v;
  } else {
    int row = (blk - 6144) * 4 + (threadIdx.x >> 6);
    ln_body(hin, ybo, lnw + d * 768, lnb + d * 768, row, 6304);
  }
}

// ============================================================================
// mm256: 3-ring counted-vmcnt MFMA GEMM, BM=256 x BN=128, BK=32, 512 thr /
// 8 waves (4m x 2n), per-wave 64x64. LDS = 3 x 24KB = 72KB -> 2 blocks/CU.
// r6-proven schedule: prologue vmcnt(3), loop vmcnt(2).
// EPI: 1=qkv (split bias, Q/K->bf16, V->vt), 3=fc1 (bias+gelu->bf16).
// ============================================================================
template <int EPI>
__global__ __launch_bounds__(512, 4) void mm256_k(
    const bf16* __restrict__ A, const bf16* __restrict__ W,
    const float* __restrict__ bias, const float* __restrict__ bias2,
    void* __restrict__ Cout, bf16* __restrict__ vtg,
    int M, int Nn, int K) {
  constexpr int BUFSZ = 24576;
  __shared__ __attribute__((aligned(16))) char lds[3 * BUFSZ];
  const int tid = threadIdx.x;
  const int lane = tid & 63, wave = tid >> 6;
  const int wr = wave >> 1, wc = wave & 1;
  const int l15 = lane & 15, lg = lane >> 4;
  const int row0 = blockIdx.x * 256, n0 = blockIdx.y * 128;
  const int nt = K >> 5, ntm1 = nt - 1;

  const bf16 *gA0, *gA1, *gB0;
  int dA0, dA1, dB0;
  {
    int s = tid * 16;
    int r = s >> 6, cl = ((s >> 4) & 3) ^ ((r >> 1) & 3);
    gA0 = A + (size_t)(row0 + r) * K + cl * 8;  dA0 = s;
    s = 8192 + tid * 16;
    r = s >> 6; cl = ((s >> 4) & 3) ^ ((r >> 1) & 3);
    gA1 = A + (size_t)(row0 + r) * K + cl * 8;  dA1 = s;
    s = tid * 16;
    r = s >> 6; cl = ((s >> 4) & 3) ^ ((r >> 1) & 3);
    gB0 = W + (size_t)(n0 + r) * K + cl * 8;    dB0 = 16384 + s;
  }
  int oA[4], oB[4];
#pragma unroll
  for (int m = 0; m < 4; m++) {
    int r = wr * 64 + m * 16 + l15;
    oA[m] = (r << 6) | ((lg ^ ((r >> 1) & 3)) << 4);
  }
#pragma unroll
  for (int n = 0; n < 4; n++) {
    int r = wc * 64 + n * 16 + l15;
    oB[n] = 16384 + ((r << 6) | ((lg ^ ((r >> 1) & 3)) << 4));
  }

  f32x4 acc[4][4];
#pragma unroll
  for (int m = 0; m < 4; m++)
#pragma unroll
    for (int n = 0; n < 4; n++) acc[m][n] = (f32x4){0.f, 0.f, 0.f, 0.f};

  GLD(gA0, lds + dA0); GLD(gA1, lds + dA1); GLD(gB0, lds + dB0);
  GLD(gA0 + 32, lds + BUFSZ + dA0); GLD(gA1 + 32, lds + BUFSZ + dA1);
  GLD(gB0 + 32, lds + BUFSZ + dB0);
  asm volatile("s_waitcnt vmcnt(3)" ::: "memory");
  __builtin_amdgcn_s_barrier();
  __builtin_amdgcn_sched_barrier(0);

#define MB(RB, WB, tt)                                                        \
  {                                                                           \
    int ks = (tt) + 2; if (ks > ntm1) ks = ntm1; ks <<= 5;                    \
    char* wb = lds + (WB) * BUFSZ;                                            \
    GLD(gA0 + ks, wb + dA0); GLD(gA1 + ks, wb + dA1);                         \
    GLD(gB0 + ks, wb + dB0);                                                  \
    const char* rb = lds + (RB) * BUFSZ;                                      \
    short8 a[4], b[4];                                                        \
    _Pragma("unroll") for (int m = 0; m < 4; m++)                             \
      a[m] = *(const short8*)(rb + oA[m]);                                    \
    _Pragma("unroll") for (int n = 0; n < 4; n++)                             \
      b[n] = *(const short8*)(rb + oB[n]);                                    \
    __builtin_amdgcn_s_setprio(1);                                            \
    _Pragma("unroll") for (int m = 0; m < 4; m++)                             \
      _Pragma("unroll") for (int n = 0; n < 4; n++)                           \
        acc[m][n] = __builtin_amdgcn_mfma_f32_16x16x32_bf16(a[m], b[n], acc[m][n], 0, 0, 0); \
    __builtin_amdgcn_s_setprio(0);                                            \
    __builtin_amdgcn_sched_barrier(0);                                        \
    asm volatile("s_waitcnt vmcnt(2)" ::: "memory");                          \
    __builtin_amdgcn_s_barrier();                                             \
    __builtin_amdgcn_sched_barrier(0);                                        \
  }

  for (int t = 0; t < nt; t += 3) {  // nt % 3 == 0
    MB(0, 2, t); MB(1, 0, t + 1); MB(2, 1, t + 2);
  }
#undef MB
  asm volatile("s_waitcnt vmcnt(0)" ::: "memory");

#pragma unroll
  for (int m = 0; m < 4; m++) {
    const int rbase = row0 + wr * 64 + m * 16 + lg * 4;
#pragma unroll
    for (int n = 0; n < 4; n++) {
      const int gc = n0 + wc * 64 + n * 16 + l15;
      f32x4 v = acc[m][n];
#pragma unroll
      for (int j = 0; j < 4; j++) {
        int gr = rbase + j;
        if (gr >= M) continue;
        float val = v[j];
        if (EPI == 1) {
          if (gc < 768) val += bias[gc];
          else if (gc >= 1536) val += bias2[gc - 1536];
          if (gc >= 1536) {
            int ob = gr / 197, nn = gr - ob * 197, hd = gc - 1536;
            vtg[(((size_t)ob * 12 + (hd >> 6)) * 64 + (hd & 63)) * NPAD + nn] =
                __float2bfloat16(val);
          } else {
            ((bf16*)Cout)[(size_t)gr * Nn + gc] = __float2bfloat16(val);
          }
        } else {  // EPI == 3
          val += bias[gc];
          val = 0.5f * val * (1.f + erff(val * 0.70710678118654752f));
          ((bf16*)Cout)[(size_t)gr * Nn + gc] = __float2bfloat16(val);
        }
      }
    }
  }
}

// ============================================================================
// mm128: 3-ring counted-vmcnt, BM=BN=128, BK=32, 256 thr / 4 waves (2x2),
// per-wave 64x64. LDS = 48KB -> 3 blocks/CU. r6 schedule: prologue vmcnt(4),
// loop vmcnt(3). EPI: 0=patch (bias, f32, remap), 2=bias+residual (f32).
// ============================================================================
template <int EPI>
__global__ __launch_bounds__(256, 3) void mm128_k(
    const bf16* __restrict__ A, const bf16* __restrict__ W,
    const float* __restrict__ bias, const float* __restrict__ Res,
    void* __restrict__ Cout, int M, int Nn, int K) {
  constexpr int BUFSZ = 16384;
  __shared__ __attribute__((aligned(16))) char lds[3 * BUFSZ];
  const int tid = threadIdx.x;
  const int lane = tid & 63, wave = tid >> 6;
  const int wr = wave >> 1, wc = wave & 1;
  const int l15 = lane & 15, lg = lane >> 4;
  const int row0 = blockIdx.x * 128, n0 = blockIdx.y * 128;
  const int nt = K >> 5, ntm1 = nt - 1;

  const bf16 *gA0, *gA1, *gB0, *gB1;
  int dA0, dA1, dB0, dB1;
  {
    int s = tid * 16;
    int r = s >> 6, cl = ((s >> 4) & 3) ^ ((r >> 1) & 3);
    gA0 = A + (size_t)(row0 + r) * K + cl * 8;  dA0 = s;
    s = 4096 + tid * 16;
    r = s >> 6; cl = ((s >> 4) & 3) ^ ((r >> 1) & 3);
    gA1 = A + (size_t)(row0 + r) * K + cl * 8;  dA1 = s;
    s = tid * 16;
    r = s >> 6; cl = ((s >> 4) & 3) ^ ((r >> 1) & 3);
    gB0 = W + (size_t)(n0 + r) * K + cl * 8;    dB0 = 8192 + s;
    s = 4096 + tid * 16;
    r = s >> 6; cl = ((s >> 4) & 3) ^ ((r >> 1) & 3);
    gB1 = W + (size_t)(n0 + r) * K + cl * 8;    dB1 = 8192 + s;
  }
  int oA[4], oB[4];
#pragma unroll
  for (int m = 0; m < 4; m++) {
    int r = wr * 64 + m * 16 + l15;
    oA[m] = (r << 6) | ((lg ^ ((r >> 1) & 3)) << 4);
  }
#pragma unroll
  for (int n = 0; n < 4; n++) {
    int r = wc * 64 + n * 16 + l15;
    oB[n] = 8192 + ((r << 6) | ((lg ^ ((r >> 1) & 3)) << 4));
  }

  f32x4 acc[4][4];
#pragma unroll
  for (int m = 0; m < 4; m++)
#pragma unroll
    for (int n = 0; n < 4; n++) acc[m][n] = (f32x4){0.f, 0.f, 0.f, 0.f};

  GLD(gA0, lds + dA0); GLD(gA1, lds + dA1);
  GLD(gB0, lds + dB0); GLD(gB1, lds + dB1);
  GLD(gA0 + 32, lds + BUFSZ + dA0); GLD(gA1 + 32, lds + BUFSZ + dA1);
  GLD(gB0 + 32, lds + BUFSZ + dB0); GLD(gB1 + 32, lds + BUFSZ + dB1);
  asm volatile("s_waitcnt vmcnt(4)" ::: "memory");
  __builtin_amdgcn_s_barrier();
  __builtin_amdgcn_sched_barrier(0);

#define MB(RB, WB, tt)                                                        \
  {                                                                           \
    int ks = (tt) + 2; if (ks > ntm1) ks = ntm1; ks <<= 5;                    \
    char* wb = lds + (WB) * BUFSZ;                                            \
    GLD(gA0 + ks, wb + dA0); GLD(gA1 + ks, wb + dA1);                         \
    GLD(gB0 + ks, wb + dB0); GLD(gB1 + ks, wb + dB1);                         \
    const char* rb = lds + (RB) * BUFSZ;                                      \
    short8 a[4], b[4];                                                        \
    _Pragma("unroll") for (int m = 0; m < 4; m++)                             \
      a[m] = *(const short8*)(rb + oA[m]);                                    \
    _Pragma("unroll") for (int n = 0; n < 4; n++)                             \
      b[n] = *(const short8*)(rb + oB[n]);                                    \
    __builtin_amdgcn_s_setprio(1);                                            \
    _Pragma("unroll") for (int m = 0; m < 4; m++)                             \
      _Pragma("unroll") for (int n = 0; n < 4; n++)                           \
        acc[m][n] = __builtin_amdgcn_mfma_f32_16x16x32_bf16(a[m], b[n], acc[m][n], 0, 0, 0); \
    __builtin_amdgcn_s_setprio(0);                                            \
    __builtin_amdgcn_sched_barrier(0);                                        \
    asm volatile("s_waitcnt vmcnt(3)" ::: "memory");                          \
    __builtin_amdgcn_s_barrier();                                             \
    __builtin_amdgcn_sched_barrier(0);                                        \
  }

  for (int t = 0; t < nt; t += 3) {  // nt % 3 == 0
    MB(0, 2, t); MB(1, 0, t + 1); MB(2, 1, t + 2);
  }
#undef MB
  asm volatile("s_waitcnt vmcnt(0)" ::: "memory");

#pragma unroll
  for (int m = 0; m < 4; m++) {
    const int rbase = row0 + wr * 64 + m * 16 + lg * 4;
#pragma unroll
    for (int n = 0; n < 4; n++) {
      const int gc = n0 + wc * 64 + n * 16 + l15;
      f32x4 v = acc[m][n];
#pragma unroll
      for (int j = 0; j < 4; j++) {
        int gr = rbase + j;
        if (gr >= M) continue;
        float val = v[j] + bias[gc];
        if (EPI == 2) val += Res[(size_t)gr * Nn + gc];
        int orow = (EPI == 0) ? (gr + gr / 196 + 1) : gr;
        ((float*)Cout)[(size_t)orow * Nn + gc] = val;
      }
    }
  }
}

// ---------------- standalone LN (used for LN2) -------------------------------
__global__ __launch_bounds__(256) void ln_k(const float* __restrict__ in,
                                            bf16* __restrict__ outp,
                                            const float* __restrict__ w,
                                            const float* __restrict__ b,
                                            int rows) {
  int row = blockIdx.x * 4 + (threadIdx.x >> 6);
  ln_body(in, outp, w, b, row, rows);
}

// ---------------- MFMA flash attention --------------------------------------
__device__ __forceinline__ unsigned pkbf(float a, float b) {
  union { bf16 h; unsigned short u; } ua, ub;
  ua.h = __float2bfloat16(a); ub.h = __float2bfloat16(b);
  return ((unsigned)ub.u << 16) | (unsigned)ua.u;
}

__global__ __launch_bounds__(256) void attn2_k(const bf16* __restrict__ qkvb,
                                               const bf16* __restrict__ vtg,
                                               const float* __restrict__ biasT,
                                               bf16* __restrict__ outp) {
  __shared__ bf16 Ks[NPAD * 64];
  __shared__ bf16 Vt[64 * NPAD];
  __shared__ bf16 Ps[4][64 * 32];
  __shared__ float denl[4][64];

  const int bh = blockIdx.x;
  const int b = bh / 12, h = bh % 12;
  const int tid = threadIdx.x;
  const int wave = tid >> 6, lane = tid & 63;
  const int l15 = lane & 15, lg = lane >> 4;
  const int qbase = wave * 64;

  const bf16* vsrc = vtg + (size_t)bh * 64 * NPAD;
#pragma unroll
  for (int i = 0; i < 7; i++) {
    int c = i * 256 + tid;
    GLD(vsrc + c * 8, Vt + c * 8);
  }
#pragma unroll
  for (int i = 0; i < 7; i++) {
    int slot = i * 256 + tid;
    int r = slot >> 3, c8 = (slot & 7) * 8;
    int rg = min(r, NTOK - 1);
    short8 kv = *(const short8*)(qkvb + (size_t)(b * NTOK + rg) * 2304 + 768 + h * 64 + c8);
    int byte = (r * 128 + c8 * 2) ^ ((r & 7) << 4);
    *(short8*)((char*)Ks + byte) = kv;
  }
  short8 qf[4][2];
#pragma unroll
  for (int nf = 0; nf < 4; nf++) {
    int n = qbase + nf * 16 + l15;
    const bf16* qp = qkvb + (size_t)(b * NTOK + min(n, NTOK - 1)) * 2304 + h * 64;
    qf[nf][0] = *(const short8*)(qp + lg * 8);
    qf[nf][1] = *(const short8*)(qp + 32 + lg * 8);
  }
  __syncthreads();

  f32x4 Oacc[4][4];
#pragma unroll
  for (int i = 0; i < 4; i++)
#pragma unroll
    for (int j = 0; j < 4; j++) Oacc[i][j] = (f32x4){0.f, 0.f, 0.f, 0.f};
  float den[4] = {0.f, 0.f, 0.f, 0.f};
  const float* bT = biasT + (size_t)h * NPAD * 256;
  char* pw = (char*)&Ps[wave][0];

  for (int c = 0; c < 7; c++) {
    const int m0 = c * 32;
    f32x4 st[2][4];
#pragma unroll
    for (int mf = 0; mf < 2; mf++)
#pragma unroll
      for (int nf = 0; nf < 4; nf++) st[mf][nf] = (f32x4){0.f, 0.f, 0.f, 0.f};
#pragma unroll
    for (int kk = 0; kk < 2; kk++) {
      short8 af[2];
#pragma unroll
      for (int mf = 0; mf < 2; mf++) {
        int m = m0 + mf * 16 + l15;
        int byte = (m * 128 + kk * 64 + lg * 16) ^ ((m & 7) << 4);
        af[mf] = *(const short8*)((const char*)Ks + byte);
      }
#pragma unroll
      for (int mf = 0; mf < 2; mf++)
#pragma unroll
        for (int nf = 0; nf < 4; nf++)
          st[mf][nf] = __builtin_amdgcn_mfma_f32_16x16x32_bf16(af[mf], qf[nf][kk], st[mf][nf], 0, 0, 0);
    }
#pragma unroll
    for (int mf = 0; mf < 2; mf++) {
      int mrow = m0 + mf * 16 + lg * 4;
#pragma unroll
      for (int nf = 0; nf < 4; nf++) {
        int n = qbase + nf * 16 + l15;
        float p0 = __expf(st[mf][nf][0] * 0.125f + bT[(mrow + 0) * 256 + n]);
        float p1 = __expf(st[mf][nf][1] * 0.125f + bT[(mrow + 1) * 256 + n]);
        float p2 = __expf(st[mf][nf][2] * 0.125f + bT[(mrow + 2) * 256 + n]);
        float p3 = __expf(st[mf][nf][3] * 0.125f + bT[(mrow + 3) * 256 + n]);
        den[nf] += (p0 + p1) + (p2 + p3);
        int nl = nf * 16 + l15;
        int byte = (nl * 64 + (mf * 16 + lg * 4) * 2) ^ ((nl & 7) << 4);
        *(unsigned*)(pw + byte) = pkbf(p0, p1);
        *(unsigned*)(pw + byte + 4) = pkbf(p2, p3);
      }
    }
    short8 pa[4], vb[4];
#pragma unroll
    for (int nf = 0; nf < 4; nf++) {
      int nl = nf * 16 + l15;
      int byte = (nl * 64 + lg * 16) ^ ((nl & 7) << 4);
      pa[nf] = *(const short8*)((const char*)pw + byte);
    }
#pragma unroll
    for (int df = 0; df < 4; df++) {
      int d = df * 16 + l15;
      vb[df] = *(const short8*)(Vt + d * NPAD + m0 + lg * 8);
    }
#pragma unroll
    for (int nf = 0; nf < 4; nf++)
#pragma unroll
      for (int df = 0; df < 4; df++)
        Oacc[nf][df] = __builtin_amdgcn_mfma_f32_16x16x32_bf16(pa[nf], vb[df], Oacc[nf][df], 0, 0, 0);
  }

#pragma unroll
  for (int nf = 0; nf < 4; nf++) {
    den[nf] += __shfl_xor(den[nf], 16);
    den[nf] += __shfl_xor(den[nf], 32);
    denl[wave][nf * 16 + l15] = den[nf];
  }
  float inv[4][4];
#pragma unroll
  for (int nf = 0; nf < 4; nf++)
#pragma unroll
    for (int j = 0; j < 4; j++)
      inv[nf][j] = 1.f / denl[wave][nf * 16 + lg * 4 + j];
#pragma unroll
  for (int nf = 0; nf < 4; nf++) {
#pragma unroll
    for (int df = 0; df < 4; df++) {
#pragma unroll
      for (int j = 0; j < 4; j++) {
        int n = qbase + nf * 16 + lg * 4 + j;
        if (n < NTOK)
          outp[(size_t)(b * NTOK + n) * 768 + h * 64 + df * 16 + l15] =
              __float2bfloat16(Oacc[nf][df][j] * inv[nf][j]);
      }
    }
  }
}

// ---------------- mean-pool + LayerNorm -------------------------------------
__device__ __forceinline__ float block_sum(float v, float* sm4) {
#pragma unroll
  for (int o = 32; o; o >>= 1) v += __shfl_down(v, o);
  __syncthreads();
  if ((threadIdx.x & 63) == 0) sm4[threadIdx.x >> 6] = v;
  __syncthreads();
  return sm4[0] + sm4[1] + sm4[2] + sm4[3];
}

__global__ __launch_bounds__(256) void pool_ln_k(const float* __restrict__ h,
                                                 const float* __restrict__ w,
                                                 const float* __restrict__ bi,
                                                 float* __restrict__ feat) {
  __shared__ float sm4[4];
  int b = blockIdx.x, tid = threadIdx.x;
  float vals[3];
  float local = 0.f;
#pragma unroll
  for (int j = 0; j < 3; j++) {
    int e = tid + j * 256;
    float s = 0.f;
    for (int nn = 1; nn < 197; nn++) s += h[((size_t)(b * 197 + nn)) * 768 + e];
    s *= (1.f / 196.f);
    vals[j] = s;
    local += s;
  }
  float tot = block_sum(local, sm4);
  float mean = tot * (1.f / 768.f);
  float lv = 0.f;
#pragma unroll
  for (int j = 0; j < 3; j++) { float d = vals[j] - mean; lv += d * d; }
  float vtot = block_sum(lv, sm4);
  float rs = rsqrtf(vtot * (1.f / 768.f) + 1e-5f);
#pragma unroll
  for (int j = 0; j < 3; j++) {
    int e = tid + j * 256;
    feat[(size_t)b * 768 + e] = (vals[j] - mean) * rs * w[e] + bi[e];
  }
}

// ---------------- small fp32 GEMM for the head ------------------------------
__global__ __launch_bounds__(256) void head_k(const float* __restrict__ A,
                                              const float* __restrict__ W,
                                              const float* __restrict__ bias,
                                              float* __restrict__ C,
                                              int M, int Nn, int K) {
  __shared__ float As[16][64 + 4];
  __shared__ float Bs[16][64 + 4];
  int tid = threadIdx.x;
  int tx = tid & 15, ty = tid >> 4;
  int row0 = blockIdx.x * 64, n0 = blockIdx.y * 64;
  int lrow = tid >> 2;
  int kq = (tid & 3) * 4;
  float acc[4][4];
#pragma unroll
  for (int i = 0; i < 4; i++)
#pragma unroll
    for (int j = 0; j < 4; j++) acc[i][j] = 0.f;
  for (int k0 = 0; k0 < K; k0 += 16) {
    float4 av = make_float4(0.f, 0.f, 0.f, 0.f);
    if (row0 + lrow < M) av = *(const float4*)&A[(size_t)(row0 + lrow) * K + k0 + kq];
    As[kq + 0][lrow] = av.x; As[kq + 1][lrow] = av.y;
    As[kq + 2][lrow] = av.z; As[kq + 3][lrow] = av.w;
    float4 bv = make_float4(0.f, 0.f, 0.f, 0.f);
    if (n0 + lrow < Nn) bv = *(const float4*)&W[(size_t)(n0 + lrow) * K + k0 + kq];
    Bs[kq + 0][lrow] = bv.x; Bs[kq + 1][lrow] = bv.y;
    Bs[kq + 2][lrow] = bv.z; Bs[kq + 3][lrow] = bv.w;
    __syncthreads();
#pragma unroll
    for (int kk = 0; kk < 16; kk++) {
      float4 a = *(const float4*)&As[kk][ty * 4];
      float4 b = *(const float4*)&Bs[kk][tx * 4];
      float aa[4] = {a.x, a.y, a.z, a.w};
      float bb[4] = {b.x, b.y, b.z, b.w};
#pragma unroll
      for (int i = 0; i < 4; i++)
#pragma unroll
        for (int j = 0; j < 4; j++) acc[i][j] = fmaf(aa[i], bb[j], acc[i][j]);
    }
    __syncthreads();
  }
#pragma unroll
  for (int i = 0; i < 4; i++) {
    int gr = row0 + ty * 4 + i;
    if (gr >= M) continue;
#pragma unroll
    for (int j = 0; j < 4; j++) {
      int gc = n0 + tx * 4 + j;
      if (gc >= Nn) continue;
      C[(size_t)gr * Nn + gc] = acc[i][j] + bias[gc];
    }
  }
}

// ============================================================================
extern "C" void kernel_launch(void* const* d_in, const int* in_sizes, int n_in,
                              void* d_out, int out_size, void* d_ws, size_t ws_size,
                              hipStream_t stream) {
  const float* x       = (const float*)d_in[0];
  const float* patch_w = (const float*)d_in[1];
  const float* patch_b = (const float*)d_in[2];
  const float* cls_tok = (const float*)d_in[3];
  const float* ln1_w   = (const float*)d_in[4];
  const float* ln1_b   = (const float*)d_in[5];
  const float* qkv_w   = (const float*)d_in[6];
  const float* q_bias  = (const float*)d_in[7];
  const float* v_bias  = (const float*)d_in[8];
  const float* rel_tab = (const float*)d_in[9];
  const float* proj_w  = (const float*)d_in[10];
  const float* proj_b  = (const float*)d_in[11];
  const float* ln2_w   = (const float*)d_in[12];
  const float* ln2_b   = (const float*)d_in[13];
  const float* fc1_w   = (const float*)d_in[14];
  const float* fc1_b   = (const float*)d_in[15];
  const float* fc2_w   = (const float*)d_in[16];
  const float* fc2_b   = (const float*)d_in[17];
  const float* fcn_w   = (const float*)d_in[18];
  const float* fcn_b   = (const float*)d_in[19];
  const float* head_w  = (const float*)d_in[20];
  const float* head_b  = (const float*)d_in[21];
  float* outp = (float*)d_out;

  char* wsb = (char*)d_ws;
  float* h    = (float*)wsb;  wsb += 19365888;   // [6304][768] f32
  bf16* bigb  = (bf16*)wsb;   wsb += 29048832;   // [6304][2304]
  bf16* yb    = (bf16*)wsb;   wsb += 9830400;    // [6400][768]
  bf16* hid   = (bf16*)wsb;   wsb += 39321600;   // [6400][3072]
  bf16* wl    = (bf16*)wsb;   wsb += 14155776;
  bf16* vt_g  = (bf16*)wsb;   wsb += 11010048;   // [32][12][64][224]
  float* biasT = (float*)wsb; wsb += 2752512;    // [12][224][256] f32
  float* feat = (float*)wsb;

  const int M = 6304;

  pre_k<<<21888, 256, 0, stream>>>(x, patch_w, cls_tok, vt_g, hid, wl, h);
  mm128_k<0><<<dim3(49, 6), 256, 0, stream>>>(
      hid, wl, patch_b, nullptr, h, 6272, 768, 768);

  for (int d = 0; d < 12; d++) {
    prepln_k<<<7720, 256, 0, stream>>>(qkv_w, proj_w, fc1_w, fc2_w, rel_tab,
                                       wl, biasT, h, yb, ln1_w, ln1_b, d);
    mm256_k<1><<<dim3(25, 18), 512, 0, stream>>>(
        yb, wl, q_bias + d * 768, v_bias + d * 768, bigb, vt_g, M, 2304, 768);
    attn2_k<<<32 * NHEAD, 256, 0, stream>>>(bigb, vt_g, biasT, yb);
    mm128_k<2><<<dim3(50, 6), 256, 0, stream>>>(
        yb, wl + O_PROJ, proj_b + d * 768, h, h, M, 768, 768);
    ln_k<<<dim3((M + 3) / 4), 256, 0, stream>>>(h, yb, ln2_w + d * 768, ln2_b + d * 768, M);
    mm256_k<3><<<dim3(25, 24), 512, 0, stream>>>(
        yb, wl + O_FC1, fc1_b + d * 3072, nullptr, hid, nullptr, M, 3072, 768);
    mm128_k<2><<<dim3(50, 6), 256, 0, stream>>>(
        hid, wl + O_FC2, fc2_b + d * 768, h, h, M, 768, 3072);
  }

  pool_ln_k<<<32, 256, 0, stream>>>(h, fcn_w, fcn_b, feat);
  {
    dim3 g(1, (1000 + 63) / 64);
    head_k<<<g, 256, 0, stream>>>(feat, head_w, head_b, outp, 32, 1000, 768);
  }
}